// Round 10
// baseline (266.267 us; speedup 1.0000x reference)
//
#include <hip/hip_runtime.h>
#include <hip/hip_bf16.h>

#define T_TOK 8192
#define DH    1024
#define NE    8
#define TK    4

typedef unsigned short u16;
typedef __bf16 bf16x8 __attribute__((ext_vector_type(8)));
typedef float  f32x4  __attribute__((ext_vector_type(4)));

__device__ __forceinline__ u16 f2b(float f) {
    union { float f; unsigned u; } v; v.f = f;
    unsigned u = v.u;
    u += 0x7FFFu + ((u >> 16) & 1u);   // round-to-nearest-even
    return (u16)(u >> 16);
}
__device__ __forceinline__ float b2f(u16 h) {
    union { unsigned u; float f; } v; v.u = ((unsigned)h) << 16;
    return v.f;
}
// async global->LDS, 16B per lane; LDS dest = wave-uniform base + lane*16 (linear!)
__device__ __forceinline__ void glds16(const u16* g, u16* l) {
    __builtin_amdgcn_global_load_lds((const __attribute__((address_space(1))) void*)g,
                                     (__attribute__((address_space(3))) void*)l, 16, 0, 0);
}

#define FENCE() asm volatile("" ::: "memory")
#define SBAR()  do { FENCE(); __builtin_amdgcn_s_barrier(); FENCE(); } while (0)
// rule 18: hipcc can hoist reg-only MFMA past an inline-asm lgkmcnt; fence with sched_barrier(0)
#define WAITLGKM0() do { asm volatile("s_waitcnt lgkmcnt(0)" ::: "memory"); \
                         __builtin_amdgcn_sched_barrier(0); } while (0)
#define WAITVM(n) asm volatile("s_waitcnt vmcnt(" #n ")" ::: "memory")

// ---------------- fused prep: cast W (blocks 0..1023, 2 tiles each) + router (1024..2047) ----------------
__global__ __launch_bounds__(512) void prep_kernel(
    const float* __restrict__ W, u16* __restrict__ wbt,
    const float* __restrict__ x, const float* __restrict__ Wg, const float* __restrict__ bg,
    u16* __restrict__ xb,
    int* __restrict__ bucket_tok, float* __restrict__ bucket_w,
    int* __restrict__ tk_e, float* __restrict__ tk_w,
    int* __restrict__ cnt, float* __restrict__ probsum)
{
    __shared__ float tile2[2][64][65];   // cast path (33.3 KB)
    __shared__ int   lcnt[NE];
    __shared__ float lprob[NE];
    __shared__ int   gbase[NE];

    const int bid = blockIdx.x;
    const int tid = threadIdx.x;

    if (bid < 1024) {
        // ------- cast W -> bf16, transposed to [e][f][d]; two 64x64 tiles per block -------
        const int half = tid >> 8;            // 0..1
        const int tloc = tid & 255;
        const int r  = tloc >> 4;             // 0..15
        const int c4 = (tloc & 15) * 4;       // 0,4,...,60
        float (*tile)[65] = tile2[half];
        const int jc = bid * 2 + half;        // 0..2047
        const int f0 = (jc & 15) * 64;
        const int d0 = ((jc >> 4) & 15) * 64;
        const int e  = jc >> 8;
        const float* src = W + ((size_t)e << 20) + (size_t)d0 * DH + f0;
        #pragma unroll
        for (int i = 0; i < 4; i++) {
            const int row = i * 16 + r;
            const float4 v = *(const float4*)(src + (size_t)row * DH + c4);
            tile[row][c4]     = v.x;
            tile[row][c4 + 1] = v.y;
            tile[row][c4 + 2] = v.z;
            tile[row][c4 + 3] = v.w;
        }
        __syncthreads();
        u16* dst = wbt + ((size_t)e << 20) + (size_t)f0 * DH + d0;
        #pragma unroll
        for (int i = 0; i < 4; i++) {
            const int orow = i * 16 + r;      // f-index within tile
            ushort4 o;
            o.x = f2b(tile[c4][orow]);
            o.y = f2b(tile[c4 + 1][orow]);
            o.z = f2b(tile[c4 + 2][orow]);
            o.w = f2b(tile[c4 + 3][orow]);
            *(ushort4*)(dst + (size_t)orow * DH + c4) = o;
        }
        return;
    }

    // ------- router: logits + softmax + top4 + buckets, fused x->bf16 cast -------
    const int wv = tid >> 6, lane = tid & 63;
    const int t = (bid - 1024) * 8 + wv;
    if (tid < NE) { lcnt[tid] = 0; lprob[tid] = 0.f; }
    __syncthreads();

    float a[NE] = {};
    {
        const float* xr = x + (size_t)t * DH;
        u16* xbr = xb + (size_t)t * DH;
        const float4* wg = (const float4*)Wg;   // row d -> wg[2d] (e0..3), wg[2d+1] (e4..7)
        #pragma unroll
        for (int it = 0; it < 4; it++) {
            const int d = it * 256 + lane * 4;
            const float4 v = *(const float4*)(xr + d);
            ushort4 o;
            o.x = f2b(v.x); o.y = f2b(v.y); o.z = f2b(v.z); o.w = f2b(v.w);
            *(ushort4*)(xbr + d) = o;
            const float4 w0l = wg[2 * (d + 0)], w0h = wg[2 * (d + 0) + 1];
            const float4 w1l = wg[2 * (d + 1)], w1h = wg[2 * (d + 1) + 1];
            const float4 w2l = wg[2 * (d + 2)], w2h = wg[2 * (d + 2) + 1];
            const float4 w3l = wg[2 * (d + 3)], w3h = wg[2 * (d + 3) + 1];
            a[0] += v.x * w0l.x + v.y * w1l.x + v.z * w2l.x + v.w * w3l.x;
            a[1] += v.x * w0l.y + v.y * w1l.y + v.z * w2l.y + v.w * w3l.y;
            a[2] += v.x * w0l.z + v.y * w1l.z + v.z * w2l.z + v.w * w3l.z;
            a[3] += v.x * w0l.w + v.y * w1l.w + v.z * w2l.w + v.w * w3l.w;
            a[4] += v.x * w0h.x + v.y * w1h.x + v.z * w2h.x + v.w * w3h.x;
            a[5] += v.x * w0h.y + v.y * w1h.y + v.z * w2h.y + v.w * w3h.y;
            a[6] += v.x * w0h.z + v.y * w1h.z + v.z * w2h.z + v.w * w3h.z;
            a[7] += v.x * w0h.w + v.y * w1h.w + v.z * w2h.w + v.w * w3h.w;
        }
    }
    #pragma unroll
    for (int e = 0; e < NE; e++) {
        float v = a[e];
        #pragma unroll
        for (int off = 32; off > 0; off >>= 1) v += __shfl_down(v, off);
        a[e] = v;
    }

    int idx4[TK]; float w4[TK]; int off4[TK];
    if (lane == 0) {
        float logits[NE], probs[NE];
        float mx = -1e30f;
        #pragma unroll
        for (int e = 0; e < NE; e++) { logits[e] = a[e] + bg[e]; mx = fmaxf(mx, logits[e]); }
        float Z = 0.f;
        #pragma unroll
        for (int e = 0; e < NE; e++) { probs[e] = expf(logits[e] - mx); Z += probs[e]; }
        const float rZ = 1.f / Z;
        #pragma unroll
        for (int e = 0; e < NE; e++) probs[e] *= rZ;

        float rem2[NE];
        #pragma unroll
        for (int e = 0; e < NE; e++) rem2[e] = probs[e];
        float s4 = 0.f;
        #pragma unroll
        for (int k = 0; k < TK; k++) {   // strict > scan from 0 == jax tie-break (lowest idx)
            int best = 0; float bv = rem2[0];
            #pragma unroll
            for (int e = 1; e < NE; e++) if (rem2[e] > bv) { bv = rem2[e]; best = e; }
            idx4[k] = best; w4[k] = bv; s4 += bv; rem2[best] = -1e30f;
        }
        const float rs = 1.f / (s4 + 1e-6f);
        #pragma unroll
        for (int k = 0; k < TK; k++) {
            w4[k] *= rs;
            tk_e[t * TK + k] = idx4[k];
            tk_w[t * TK + k] = w4[k];
            off4[k] = atomicAdd(&lcnt[idx4[k]], 1);
        }
        #pragma unroll
        for (int e = 0; e < NE; e++) atomicAdd(&lprob[e], probs[e]);
    }
    __syncthreads();
    if (tid < NE) {
        gbase[tid] = atomicAdd(&cnt[tid], lcnt[tid]);
        atomicAdd(&probsum[tid], lprob[tid]);
    }
    __syncthreads();
    if (lane == 0) {
        #pragma unroll
        for (int k = 0; k < TK; k++) {
            const int e = idx4[k];
            const int slot = gbase[e] + off4[k];
            bucket_tok[e * T_TOK + slot] = (t << 2) | k;
            bucket_w[e * T_TOK + slot]   = w4[k];
        }
    }
}

// ---------------- grouped gather GEMM, 256x256 / BK=64 / 8-wave / 4-phase-per-K-tile ----------------
// R10 = R9 inner loop VERBATIM; static j-loop replaced by DYNAMIC tile claiming:
//  - per-expert atomic counters tcnt[e]; block (XCD heuristic e0=bid&7) drains its own
//    expert first (keeps the L2 affinity that cut FETCH to 48MB), then steals from
//    e0+1, e0+2, ... Claims exclusive, block-uniform (lane0 atomic + LDS broadcast via
//    the existing barrier pair). Makespan ~2.0 units vs static ~2.45 (Occupancy 20.4%).
//  - Full tiles only; tail kernel unchanged.
__global__ __launch_bounds__(512, 2) void moe_gemm_kernel(
    const u16* __restrict__ xb, const u16* __restrict__ wbt,
    const int* __restrict__ bucket_tok, const float* __restrict__ bucket_w,
    const int* __restrict__ cnt, int* __restrict__ tcnt, u16* __restrict__ y)
{
    __shared__ u16 As[2][256 * 64];   // 64 KB
    __shared__ u16 Bs[2][256 * 64];   // 64 KB
    __shared__ int   s_tok[256];
    __shared__ float s_w[256];
    __shared__ int   s_claim;

    const int tid  = threadIdx.x;
    const int lane = tid & 63;
    const int wid  = tid >> 6;            // 0..7
    const int wr   = wid >> 2;            // 0..1 (M)
    const int wc   = wid & 3;             // 0..3 (N)
    const int fr   = lane & 15;
    const int fq   = (lane >> 4) * 8;
    const int swz  = (fr & 7) << 3;       // u16-index XOR for frag reads
    const int gsw  = ((lane & 7) ^ (lane >> 3)) * 8;  // pre-swizzled global u16 col for staging
    const int crow = lane >> 3;           // row within 8-row chunk

    const int ALb = 2 * wid + (wid >= 4 ? 8 : 0);
    const int AHb = ALb + 8;
    const int BLb = (wid >> 1) * 8 + (wid & 1) * 2;
    const int BHb = BLb + 4;

    const int e0 = blockIdx.x & 7;         // XCD-affinity seed

    for (int ee = 0; ee < NE; ++ee) {
        const int e  = (e0 + ee) & 7;
        const int M  = cnt[e];
        const int nt = (M >> 8) << 2;      // full tiles only (floor(M/256) * 4 n-blocks)
        while (true) {
            __syncthreads();               // WAR on s_tok/s_w + claim broadcast
            if (tid == 0) s_claim = atomicAdd(&tcnt[e], 1);
            __syncthreads();
            const int t = s_claim;
            if (t >= nt) break;            // uniform across block
            const int m0 = (t >> 2) << 8;
            const int n0 = (t & 3) << 8;

            if (tid < 256) {
                s_tok[tid] = bucket_tok[e * T_TOK + m0 + tid];
                s_w[tid]   = bucket_w[e * T_TOK + m0 + tid];
            }
            __syncthreads();

            const int rAL0 = ALb * 8 + crow, rAL1 = rAL0 + 8;
            const int rAH0 = AHb * 8 + crow, rAH1 = rAH0 + 8;
            const int tAL0 = s_tok[rAL0], tAL1 = s_tok[rAL1];
            const int tAH0 = s_tok[rAH0], tAH1 = s_tok[rAH1];
            const u16* gAL0 = xb + (size_t)(tAL0 >> 2) * DH + gsw;
            const u16* gAL1 = xb + (size_t)(tAL1 >> 2) * DH + gsw;
            const u16* gAH0 = xb + (size_t)(tAH0 >> 2) * DH + gsw;
            const u16* gAH1 = xb + (size_t)(tAH1 >> 2) * DH + gsw;
            const u16* wbe  = wbt + ((size_t)e << 20);
            const u16* gBL0 = wbe + (size_t)(n0 + BLb * 8 + crow) * DH + gsw;
            const u16* gBL1 = gBL0 + (size_t)8 * DH;
            const u16* gBH0 = wbe + (size_t)(n0 + BHb * 8 + crow) * DH + gsw;
            const u16* gBH1 = gBH0 + (size_t)8 * DH;

            f32x4 acc[8][4] = {};

            #pragma unroll
            for (int kt = 0; kt < 2; kt++) {
                const int ko = kt * 64; const int p = kt;
                glds16(gAL0 + ko, &As[p][ALb * 512]); glds16(gAL1 + ko, &As[p][(ALb + 1) * 512]);
                glds16(gAH0 + ko, &As[p][AHb * 512]); glds16(gAH1 + ko, &As[p][(AHb + 1) * 512]);
                glds16(gBL0 + ko, &Bs[p][BLb * 512]); glds16(gBL1 + ko, &Bs[p][(BLb + 1) * 512]);
                glds16(gBH0 + ko, &Bs[p][BHb * 512]); glds16(gBH1 + ko, &Bs[p][(BHb + 1) * 512]);
            }
            WAITVM(8);            // tile 0 resident (tile 1 in flight)
            SBAR();

            const int arow = (wr * 128 + fr) * 64;    // u16 base of this lane's A frag rows
            const int brow = (wc * 64  + fr) * 64;
            const int c0 = fq ^ swz;                  // k-half 0 column (u16)
            const int c1 = (32 + fq) ^ swz;           // k-half 1 column

            bf16x8 afL[4][2], afH[4][2], bfL[2][2], bfH[2][2];

            for (int kt = 0; kt < 16; ++kt) {
                const int p = kt & 1;
                const u16* Ap = &As[p][0];
                const u16* Bp = &Bs[p][0];

                // ---- P1: read afL(8)+bfL(4); stage A-H of kt+1 -> buf p^1; MFMA miL x njL ----
                #pragma unroll
                for (int mi = 0; mi < 4; mi++) {
                    afL[mi][0] = *(const bf16x8*)&Ap[arow + mi * 1024 + c0];
                    afL[mi][1] = *(const bf16x8*)&Ap[arow + mi * 1024 + c1];
                }
                #pragma unroll
                for (int nj = 0; nj < 2; nj++) {
                    bfL[nj][0] = *(const bf16x8*)&Bp[brow + nj * 1024 + c0];
                    bfL[nj][1] = *(const bf16x8*)&Bp[brow + nj * 1024 + c1];
                }
                if (kt >= 1 && kt <= 14) {             // A-H rows of p^1 died at end-P3 of kt-1
                    const int ko = (kt + 1) * 64; const int q = (kt + 1) & 1;
                    glds16(gAH0 + ko, &As[q][AHb * 512]);
                    glds16(gAH1 + ko, &As[q][(AHb + 1) * 512]);
                }
                asm volatile("s_waitcnt lgkmcnt(8)" ::: "memory");   // 12-read phase hint
                SBAR(); WAITLGKM0();
                __builtin_amdgcn_s_setprio(1);
                #pragma unroll
                for (int mi = 0; mi < 4; mi++)
                    #pragma unroll
                    for (int nj = 0; nj < 2; nj++) {
                        acc[mi][nj] = __builtin_amdgcn_mfma_f32_16x16x32_bf16(afL[mi][0], bfL[nj][0], acc[mi][nj], 0, 0, 0);
                        acc[mi][nj] = __builtin_amdgcn_mfma_f32_16x16x32_bf16(afL[mi][1], bfL[nj][1], acc[mi][nj], 0, 0, 0);
                    }
                __builtin_amdgcn_s_setprio(0);
                SBAR();                                // A-L/B-L rows of buf p now dead

                // ---- P2: read bfH(4); stage A-L of kt+2 -> buf p; MFMA miL x njH ----
                #pragma unroll
                for (int nj = 0; nj < 2; nj++) {
                    bfH[nj][0] = *(const bf16x8*)&Bp[brow + (nj + 2) * 1024 + c0];
                    bfH[nj][1] = *(const bf16x8*)&Bp[brow + (nj + 2) * 1024 + c1];
                }
                if (kt <= 13) {
                    const int ko = (kt + 2) * 64;
                    glds16(gAL0 + ko, &As[p][ALb * 512]);
                    glds16(gAL1 + ko, &As[p][(ALb + 1) * 512]);
                }
                SBAR(); WAITLGKM0();
                __builtin_amdgcn_s_setprio(1);
                #pragma unroll
                for (int mi = 0; mi < 4; mi++)
                    #pragma unroll
                    for (int nj = 0; nj < 2; nj++) {
                        acc[mi][nj + 2] = __builtin_amdgcn_mfma_f32_16x16x32_bf16(afL[mi][0], bfH[nj][0], acc[mi][nj + 2], 0, 0, 0);
                        acc[mi][nj + 2] = __builtin_amdgcn_mfma_f32_16x16x32_bf16(afL[mi][1], bfH[nj][1], acc[mi][nj + 2], 0, 0, 0);
                    }
                __builtin_amdgcn_s_setprio(0);
                SBAR();                                // B-H rows of buf p now dead

                // ---- P3: read afH(8); stage B-L of kt+2 -> buf p; MFMA miH x njH ----
                #pragma unroll
                for (int mi = 0; mi < 4; mi++) {
                    afH[mi][0] = *(const bf16x8*)&Ap[arow + (mi + 4) * 1024 + c0];
                    afH[mi][1] = *(const bf16x8*)&Ap[arow + (mi + 4) * 1024 + c1];
                }
                if (kt <= 13) {
                    const int ko = (kt + 2) * 64;
                    glds16(gBL0 + ko, &Bs[p][BLb * 512]);
                    glds16(gBL1 + ko, &Bs[p][(BLb + 1) * 512]);
                }
                SBAR(); WAITLGKM0();
                __builtin_amdgcn_s_setprio(1);
                #pragma unroll
                for (int mi = 0; mi < 4; mi++)
                    #pragma unroll
                    for (int nj = 0; nj < 2; nj++) {
                        acc[mi + 4][nj + 2] = __builtin_amdgcn_mfma_f32_16x16x32_bf16(afH[mi][0], bfH[nj][0], acc[mi + 4][nj + 2], 0, 0, 0);
                        acc[mi + 4][nj + 2] = __builtin_amdgcn_mfma_f32_16x16x32_bf16(afH[mi][1], bfH[nj][1], acc[mi + 4][nj + 2], 0, 0, 0);
                    }
                __builtin_amdgcn_s_setprio(0);
                SBAR();                                // A-H rows of buf p now dead

                // ---- P4: stage B-H of kt+2 -> buf p; MFMA miH x njL (regs only); counted vmcnt ----
                if (kt <= 13) {
                    const int ko = (kt + 2) * 64;
                    glds16(gBH0 + ko, &Bs[p][BHb * 512]);
                    glds16(gBH1 + ko, &Bs[p][(BHb + 1) * 512]);
                }
                __builtin_amdgcn_s_setprio(1);
                #pragma unroll
                for (int mi = 0; mi < 4; mi++)
                    #pragma unroll
                    for (int nj = 0; nj < 2; nj++) {
                        acc[mi + 4][nj] = __builtin_amdgcn_mfma_f32_16x16x32_bf16(afH[mi][0], bfL[nj][0], acc[mi + 4][nj], 0, 0, 0);
                        acc[mi + 4][nj] = __builtin_amdgcn_mfma_f32_16x16x32_bf16(afH[mi][1], bfL[nj][1], acc[mi + 4][nj], 0, 0, 0);
                    }
                __builtin_amdgcn_s_setprio(0);
                // newer-than-(kt+1) loads = kt+2's A-L,B-L,B-H = 6 -> vmcnt(6) => kt+1 resident
                if (kt <= 13)      WAITVM(6);
                else if (kt == 14) WAITVM(0);          // drain for tile 15
                SBAR();
            }

            // C/D layout: col = lane&15, row = (lane>>4)*4 + r
            const int cl = lane & 15;
            const int rb = (lane >> 4) * 4;
            #pragma unroll
            for (int mi = 0; mi < 8; mi++) {
                #pragma unroll
                for (int r = 0; r < 4; r++) {
                    const int srow = wr * 128 + mi * 16 + rb + r;
                    const int tok = s_tok[srow];
                    const float w = s_w[srow];
                    u16* yr = y + (size_t)tok * DH + (n0 + wc * 64 + cl);
                    #pragma unroll
                    for (int nj = 0; nj < 4; nj++)
                        yr[nj * 16] = f2b(acc[mi][nj][r] * w);
                }
            }
        }
    }
}

// ---------------- tail GEMM: remainder rows [floor(M/256)*256, M) per expert ----------------
__global__ __launch_bounds__(512) void moe_gemm_tail_kernel(
    const u16* __restrict__ xb, const u16* __restrict__ wbt,
    const int* __restrict__ bucket_tok, const float* __restrict__ bucket_w,
    const int* __restrict__ cnt, u16* __restrict__ y)
{
    __shared__ u16 As[2][64 * 64];    // 16 KB
    __shared__ u16 Bs[2][256 * 64];   // 64 KB
    __shared__ int   s_tok[64];
    __shared__ float s_w[64];

    const int e  = blockIdx.z;
    const int sb = blockIdx.y;         // 0..3: 64-row sub-tile of the remainder
    const int nb = blockIdx.x;         // 0..3: 256-col block
    const int M  = cnt[e];
    const int m0 = ((M >> 8) << 8) + sb * 64;
    if (m0 >= M) return;
    const int n0 = nb << 8;

    const int tid  = threadIdx.x;
    const int lane = tid & 63;
    const int w8   = tid >> 6;         // 0..7: col group (32 cols each)
    const int fr   = lane & 15;
    const int fq   = (lane >> 4) * 8;
    const int swz  = (fr & 7) << 3;
    const int gsw  = ((lane & 7) ^ (lane >> 3)) * 8;
    const int crow = lane >> 3;

    if (tid < 64) {
        const int slot = m0 + tid;
        if (slot < M) { s_tok[tid] = bucket_tok[e * T_TOK + slot]; s_w[tid] = bucket_w[e * T_TOK + slot]; }
        else          { s_tok[tid] = -1;                           s_w[tid] = 0.f; }
    }
    __syncthreads();

    const int tA = s_tok[w8 * 8 + crow];
    const u16* gA = xb + (size_t)(tA >= 0 ? (tA >> 2) : 0) * DH + gsw;
    const u16* wbe = wbt + ((size_t)e << 20);
    const u16* gB0 = wbe + (size_t)(n0 + (4 * w8 + 0) * 8 + crow) * DH + gsw;
    const u16* gB1 = wbe + (size_t)(n0 + (4 * w8 + 1) * 8 + crow) * DH + gsw;
    const u16* gB2 = wbe + (size_t)(n0 + (4 * w8 + 2) * 8 + crow) * DH + gsw;
    const u16* gB3 = wbe + (size_t)(n0 + (4 * w8 + 3) * 8 + crow) * DH + gsw;

    f32x4 acc[4][2] = {};

    #define TSTAGE(kt) do { const int p_ = (kt) & 1; const int ko_ = (kt) * 64;         \
        glds16(gA  + ko_, &As[p_][w8 * 512]);                                           \
        glds16(gB0 + ko_, &Bs[p_][(4 * w8 + 0) * 512]);                                 \
        glds16(gB1 + ko_, &Bs[p_][(4 * w8 + 1) * 512]);                                 \
        glds16(gB2 + ko_, &Bs[p_][(4 * w8 + 2) * 512]);                                 \
        glds16(gB3 + ko_, &Bs[p_][(4 * w8 + 3) * 512]); } while (0)

    TSTAGE(0); TSTAGE(1);              // 10 in flight per wave
    WAITVM(5);                         // tile 0 resident
    SBAR();

    const int c0 = fq ^ swz;
    const int c1 = (32 + fq) ^ swz;

    for (int kt = 0; kt < 16; ++kt) {
        const int p = kt & 1;
        bf16x8 af[4][2], bf[2][2];
        #pragma unroll
        for (int mi = 0; mi < 4; mi++) {
            af[mi][0] = *(const bf16x8*)&As[p][(mi * 16 + fr) * 64 + c0];
            af[mi][1] = *(const bf16x8*)&As[p][(mi * 16 + fr) * 64 + c1];
        }
        #pragma unroll
        for (int nj = 0; nj < 2; nj++) {
            bf[nj][0] = *(const bf16x8*)&Bs[p][(w8 * 32 + nj * 16 + fr) * 64 + c0];
            bf[nj][1] = *(const bf16x8*)&Bs[p][(w8 * 32 + nj * 16 + fr) * 64 + c1];
        }
        WAITLGKM0();
        __builtin_amdgcn_s_setprio(1);
        #pragma unroll
        for (int mi = 0; mi < 4; mi++)
            #pragma unroll
            for (int nj = 0; nj < 2; nj++) {
                acc[mi][nj] = __builtin_amdgcn_mfma_f32_16x16x32_bf16(af[mi][0], bf[nj][0], acc[mi][nj], 0, 0, 0);
                acc[mi][nj] = __builtin_amdgcn_mfma_f32_16x16x32_bf16(af[mi][1], bf[nj][1], acc[mi][nj], 0, 0, 0);
            }
        __builtin_amdgcn_s_setprio(0);
        SBAR();                        // all waves done reading buf p
        if (kt + 2 < 16) { TSTAGE(kt + 2); WAITVM(5); }   // tile kt+1 resident
        else if (kt == 14) WAITVM(0);                     // drain for tile 15
        if (kt < 15) SBAR();
    }
    #undef TSTAGE

    // C/D layout: col = lane&15, row = (lane>>4)*4 + r
    const int cl = lane & 15;
    const int rb = (lane >> 4) * 4;
    #pragma unroll
    for (int mi = 0; mi < 4; mi++) {
        #pragma unroll
        for (int r = 0; r < 4; r++) {
            const int srow = mi * 16 + rb + r;
            const int tok = s_tok[srow];
            if (tok < 0) continue;
            const float w = s_w[srow];
            u16* yr = y + (size_t)tok * DH + (n0 + w8 * 32 + cl);
            #pragma unroll
            for (int nj = 0; nj < 2; nj++)
                yr[nj * 16] = f2b(acc[mi][nj][r] * w);
        }
    }
}

// ---------------- combine: out[t] = sum_k y[t*4+k] + sum_k w_k*b[e_k]; block 0 does aux ----------------
__global__ __launch_bounds__(256) void combine_kernel(
    const u16* __restrict__ y, const int* __restrict__ tk_e, const float* __restrict__ tk_w,
    const float* __restrict__ bexp,
    const int* __restrict__ cnt, const float* __restrict__ probsum,
    float* __restrict__ out, float* __restrict__ out_aux)
{
    if (blockIdx.x == 0 && threadIdx.x == 0) {
        float s = 0.f;
        for (int e = 0; e < NE; e++) s += (float)cnt[e] * probsum[e];
        out_aux[0] = s * (float)NE / ((float)T_TOK * (float)T_TOK);
    }
    const int t = blockIdx.x * 2 + (threadIdx.x >> 7);
    const int c = (threadIdx.x & 127) * 8;
    float o[8] = {};
    #pragma unroll
    for (int k = 0; k < TK; k++) {
        const int e   = tk_e[t * TK + k];
        const float w = tk_w[t * TK + k];
        const u16* yp = y + ((size_t)(t * TK + k)) * DH + c;
        const ushort4 y0 = *(const ushort4*)(yp);
        const ushort4 y1 = *(const ushort4*)(yp + 4);
        const float4  b0 = *(const float4*)(bexp + (size_t)e * DH + c);
        const float4  b1 = *(const float4*)(bexp + (size_t)e * DH + c + 4);
        o[0] += b2f(y0.x) + w * b0.x;
        o[1] += b2f(y0.y) + w * b0.y;
        o[2] += b2f(y0.z) + w * b0.z;
        o[3] += b2f(y0.w) + w * b0.w;
        o[4] += b2f(y1.x) + w * b1.x;
        o[5] += b2f(y1.y) + w * b1.y;
        o[6] += b2f(y1.z) + w * b1.z;
        o[7] += b2f(y1.w) + w * b1.w;
    }
    float4 ov0 = {o[0], o[1], o[2], o[3]};
    float4 ov1 = {o[4], o[5], o[6], o[7]};
    *(float4*)(out + (size_t)t * DH + c)     = ov0;
    *(float4*)(out + (size_t)t * DH + c + 4) = ov1;
}

extern "C" void kernel_launch(void* const* d_in, const int* in_sizes, int n_in,
                              void* d_out, int out_size, void* d_ws, size_t ws_size,
                              hipStream_t stream)
{
    const float* x  = (const float*)d_in[0];
    const float* Wg = (const float*)d_in[1];
    const float* bg = (const float*)d_in[2];
    const float* W  = (const float*)d_in[3];
    const float* b  = (const float*)d_in[4];
    float* out = (float*)d_out;

    char* ws = (char*)d_ws;
    u16*   xb         = (u16*)(ws);                    // 16,777,216 B
    u16*   wbt        = (u16*)(ws + 16777216);         // 16,777,216 B
    u16*   y          = (u16*)(ws + 33554432);         // 67,108,864 B
    int*   bucket_tok = (int*)(ws + 100663296);        //    262,144 B
    float* bucket_w   = (float*)(ws + 100925440);      //    262,144 B
    int*   tk_e       = (int*)(ws + 101187584);        //    131,072 B
    float* tk_w       = (float*)(ws + 101318656);      //    131,072 B
    int*   cnt        = (int*)(ws + 101449728);        //         32 B
    float* probsum    = (float*)(ws + 101449760);      //         32 B
    int*   tcnt       = (int*)(ws + 101449792);        //         32 B (per-expert tile counters)

    hipMemsetAsync(cnt, 0, 96, stream);  // cnt + probsum + tcnt (must precede router atomics)

    prep_kernel<<<2048, 512, 0, stream>>>(W, wbt, x, Wg, bg, xb,
                                          bucket_tok, bucket_w, tk_e, tk_w, cnt, probsum);
    moe_gemm_kernel<<<dim3(256), 512, 0, stream>>>(xb, wbt, bucket_tok, bucket_w, cnt, tcnt, y);
    moe_gemm_tail_kernel<<<dim3(4, 4, NE), 512, 0, stream>>>(xb, wbt, bucket_tok, bucket_w, cnt, y);
    combine_kernel<<<4096, 256, 0, stream>>>(y, tk_e, tk_w, b, cnt, probsum, out, out + (size_t)T_TOK * DH);
}

// Round 11
// 248.249 us; speedup vs baseline: 1.0726x; 1.0726x over previous
//
#include <hip/hip_runtime.h>
#include <hip/hip_bf16.h>

#define T_TOK 8192
#define DH    1024
#define NE    8
#define TK    4

typedef unsigned short u16;
typedef __bf16 bf16x8 __attribute__((ext_vector_type(8)));
typedef float  f32x4  __attribute__((ext_vector_type(4)));

__device__ __forceinline__ u16 f2b(float f) {
    union { float f; unsigned u; } v; v.f = f;
    unsigned u = v.u;
    u += 0x7FFFu + ((u >> 16) & 1u);   // round-to-nearest-even
    return (u16)(u >> 16);
}
__device__ __forceinline__ float b2f(u16 h) {
    union { unsigned u; float f; } v; v.u = ((unsigned)h) << 16;
    return v.f;
}
// async global->LDS, 16B per lane; LDS dest = wave-uniform base + lane*16 (linear!)
__device__ __forceinline__ void glds16(const u16* g, u16* l) {
    __builtin_amdgcn_global_load_lds((const __attribute__((address_space(1))) void*)g,
                                     (__attribute__((address_space(3))) void*)l, 16, 0, 0);
}

#define FENCE() asm volatile("" ::: "memory")
#define SBAR()  do { FENCE(); __builtin_amdgcn_s_barrier(); FENCE(); } while (0)
// rule 18: hipcc can hoist reg-only MFMA past an inline-asm lgkmcnt; fence with sched_barrier(0)
#define WAITLGKM0() do { asm volatile("s_waitcnt lgkmcnt(0)" ::: "memory"); \
                         __builtin_amdgcn_sched_barrier(0); } while (0)
#define WAITVM(n) asm volatile("s_waitcnt vmcnt(" #n ")" ::: "memory")

// ---------------- fused prep: cast W (blocks 0..1023, 2 tiles each) + router (1024..2047) ----------------
__global__ __launch_bounds__(512) void prep_kernel(
    const float* __restrict__ W, u16* __restrict__ wbt,
    const float* __restrict__ x, const float* __restrict__ Wg, const float* __restrict__ bg,
    u16* __restrict__ xb,
    int* __restrict__ bucket_tok, float* __restrict__ bucket_w,
    int* __restrict__ tk_e, float* __restrict__ tk_w,
    int* __restrict__ cnt, float* __restrict__ probsum)
{
    __shared__ float tile2[2][64][65];   // cast path (33.3 KB)
    __shared__ int   lcnt[NE];
    __shared__ float lprob[NE];
    __shared__ int   gbase[NE];

    const int bid = blockIdx.x;
    const int tid = threadIdx.x;

    if (bid < 1024) {
        // ------- cast W -> bf16, transposed to [e][f][d]; two 64x64 tiles per block -------
        const int half = tid >> 8;            // 0..1
        const int tloc = tid & 255;
        const int r  = tloc >> 4;             // 0..15
        const int c4 = (tloc & 15) * 4;       // 0,4,...,60
        float (*tile)[65] = tile2[half];
        const int jc = bid * 2 + half;        // 0..2047
        const int f0 = (jc & 15) * 64;
        const int d0 = ((jc >> 4) & 15) * 64;
        const int e  = jc >> 8;
        const float* src = W + ((size_t)e << 20) + (size_t)d0 * DH + f0;
        #pragma unroll
        for (int i = 0; i < 4; i++) {
            const int row = i * 16 + r;
            const float4 v = *(const float4*)(src + (size_t)row * DH + c4);
            tile[row][c4]     = v.x;
            tile[row][c4 + 1] = v.y;
            tile[row][c4 + 2] = v.z;
            tile[row][c4 + 3] = v.w;
        }
        __syncthreads();
        u16* dst = wbt + ((size_t)e << 20) + (size_t)f0 * DH + d0;
        #pragma unroll
        for (int i = 0; i < 4; i++) {
            const int orow = i * 16 + r;      // f-index within tile
            ushort4 o;
            o.x = f2b(tile[c4][orow]);
            o.y = f2b(tile[c4 + 1][orow]);
            o.z = f2b(tile[c4 + 2][orow]);
            o.w = f2b(tile[c4 + 3][orow]);
            *(ushort4*)(dst + (size_t)orow * DH + c4) = o;
        }
        return;
    }

    // ------- router: logits + softmax + top4 + buckets, fused x->bf16 cast -------
    const int wv = tid >> 6, lane = tid & 63;
    const int t = (bid - 1024) * 8 + wv;
    if (tid < NE) { lcnt[tid] = 0; lprob[tid] = 0.f; }
    __syncthreads();

    float a[NE] = {};
    {
        const float* xr = x + (size_t)t * DH;
        u16* xbr = xb + (size_t)t * DH;
        const float4* wg = (const float4*)Wg;   // row d -> wg[2d] (e0..3), wg[2d+1] (e4..7)
        #pragma unroll
        for (int it = 0; it < 4; it++) {
            const int d = it * 256 + lane * 4;
            const float4 v = *(const float4*)(xr + d);
            ushort4 o;
            o.x = f2b(v.x); o.y = f2b(v.y); o.z = f2b(v.z); o.w = f2b(v.w);
            *(ushort4*)(xbr + d) = o;
            const float4 w0l = wg[2 * (d + 0)], w0h = wg[2 * (d + 0) + 1];
            const float4 w1l = wg[2 * (d + 1)], w1h = wg[2 * (d + 1) + 1];
            const float4 w2l = wg[2 * (d + 2)], w2h = wg[2 * (d + 2) + 1];
            const float4 w3l = wg[2 * (d + 3)], w3h = wg[2 * (d + 3) + 1];
            a[0] += v.x * w0l.x + v.y * w1l.x + v.z * w2l.x + v.w * w3l.x;
            a[1] += v.x * w0l.y + v.y * w1l.y + v.z * w2l.y + v.w * w3l.y;
            a[2] += v.x * w0l.z + v.y * w1l.z + v.z * w2l.z + v.w * w3l.z;
            a[3] += v.x * w0l.w + v.y * w1l.w + v.z * w2l.w + v.w * w3l.w;
            a[4] += v.x * w0h.x + v.y * w1h.x + v.z * w2h.x + v.w * w3h.x;
            a[5] += v.x * w0h.y + v.y * w1h.y + v.z * w2h.y + v.w * w3h.y;
            a[6] += v.x * w0h.z + v.y * w1h.z + v.z * w2h.z + v.w * w3h.z;
            a[7] += v.x * w0h.w + v.y * w1h.w + v.z * w2h.w + v.w * w3h.w;
        }
    }
    #pragma unroll
    for (int e = 0; e < NE; e++) {
        float v = a[e];
        #pragma unroll
        for (int off = 32; off > 0; off >>= 1) v += __shfl_down(v, off);
        a[e] = v;
    }

    int idx4[TK]; float w4[TK]; int off4[TK];
    if (lane == 0) {
        float logits[NE], probs[NE];
        float mx = -1e30f;
        #pragma unroll
        for (int e = 0; e < NE; e++) { logits[e] = a[e] + bg[e]; mx = fmaxf(mx, logits[e]); }
        float Z = 0.f;
        #pragma unroll
        for (int e = 0; e < NE; e++) { probs[e] = expf(logits[e] - mx); Z += probs[e]; }
        const float rZ = 1.f / Z;
        #pragma unroll
        for (int e = 0; e < NE; e++) probs[e] *= rZ;

        float rem2[NE];
        #pragma unroll
        for (int e = 0; e < NE; e++) rem2[e] = probs[e];
        float s4 = 0.f;
        #pragma unroll
        for (int k = 0; k < TK; k++) {   // strict > scan from 0 == jax tie-break (lowest idx)
            int best = 0; float bv = rem2[0];
            #pragma unroll
            for (int e = 1; e < NE; e++) if (rem2[e] > bv) { bv = rem2[e]; best = e; }
            idx4[k] = best; w4[k] = bv; s4 += bv; rem2[best] = -1e30f;
        }
        const float rs = 1.f / (s4 + 1e-6f);
        #pragma unroll
        for (int k = 0; k < TK; k++) {
            w4[k] *= rs;
            tk_e[t * TK + k] = idx4[k];
            tk_w[t * TK + k] = w4[k];
            off4[k] = atomicAdd(&lcnt[idx4[k]], 1);
        }
        #pragma unroll
        for (int e = 0; e < NE; e++) atomicAdd(&lprob[e], probs[e]);
    }
    __syncthreads();
    if (tid < NE) {
        gbase[tid] = atomicAdd(&cnt[tid], lcnt[tid]);
        atomicAdd(&probsum[tid], lprob[tid]);
    }
    __syncthreads();
    if (lane == 0) {
        #pragma unroll
        for (int k = 0; k < TK; k++) {
            const int e = idx4[k];
            const int slot = gbase[e] + off4[k];
            bucket_tok[e * T_TOK + slot] = (t << 2) | k;
            bucket_w[e * T_TOK + slot]   = w4[k];
        }
    }
}

// ---------------- grouped gather GEMM, 256x256 / BK=64 / 8-wave / 4-phase-per-K-tile ----------------
// R11 = R9 inner loop VERBATIM; static FLAT tile schedule (no atomics; R10's dynamic
// claiming regressed -10.5us from claim sync + lost A-panel locality):
//  - Global list of full tiles, expert-major: total = sum_e floor(M_e/256)*4 <= 512
//    (since sum M_e = 32768). Block lb = (bid&7)*32 + bid/8 (XCD-contiguous) takes tiles
//    g = 2*lb, 2*lb+1 -> makespan EXACTLY 2 units (vs static-per-XCD's 3 on heavy XCDs).
//  - XCD x covers g in [x*64, x*64+64): experts have ~60-68 tiles, so each XCD touches
//    ~1-2 experts -> L2 wbt affinity (FETCH 48MB) approximately preserved; consecutive
//    g pairs usually share (e, mb) -> A-panel reuse.
//  - Expert lookup = 8-entry prefix scan over cnt (block-uniform SGPR work).
__global__ __launch_bounds__(512, 2) void moe_gemm_kernel(
    const u16* __restrict__ xb, const u16* __restrict__ wbt,
    const int* __restrict__ bucket_tok, const float* __restrict__ bucket_w,
    const int* __restrict__ cnt, u16* __restrict__ y)
{
    __shared__ u16 As[2][256 * 64];   // 64 KB
    __shared__ u16 Bs[2][256 * 64];   // 64 KB
    __shared__ int   s_tok[256];
    __shared__ float s_w[256];

    const int tid  = threadIdx.x;
    const int lane = tid & 63;
    const int wid  = tid >> 6;            // 0..7
    const int wr   = wid >> 2;            // 0..1 (M)
    const int wc   = wid & 3;             // 0..3 (N)
    const int fr   = lane & 15;
    const int fq   = (lane >> 4) * 8;
    const int swz  = (fr & 7) << 3;       // u16-index XOR for frag reads
    const int gsw  = ((lane & 7) ^ (lane >> 3)) * 8;  // pre-swizzled global u16 col for staging
    const int crow = lane >> 3;           // row within 8-row chunk

    const int ALb = 2 * wid + (wid >= 4 ? 8 : 0);
    const int AHb = ALb + 8;
    const int BLb = (wid >> 1) * 8 + (wid & 1) * 2;
    const int BHb = BLb + 4;

    // flat schedule: prefix of per-expert full-tile counts (block-uniform)
    int pfx[NE + 1];
    pfx[0] = 0;
    #pragma unroll
    for (int e = 0; e < NE; e++) pfx[e + 1] = pfx[e] + ((cnt[e] >> 8) << 2);
    const int total = pfx[NE];
    const int lb = ((blockIdx.x & 7) << 5) | (blockIdx.x >> 3);   // XCD-contiguous logical id

    for (int u = 0; u < 2; ++u) {
        const int g = lb * 2 + u;
        if (g >= total) break;
        int e = 0;
        #pragma unroll
        for (int k = 1; k < NE; k++) if (pfx[k] <= g) e = k;      // uniform scan
        const int local = g - pfx[e];
        const int m0 = (local >> 2) << 8;
        const int n0 = (local & 3) << 8;
        const int M  = cnt[e];
        (void)M;

        __syncthreads();                   // s_tok/s_w + LDS reuse across tiles
        if (tid < 256) {
            s_tok[tid] = bucket_tok[e * T_TOK + m0 + tid];
            s_w[tid]   = bucket_w[e * T_TOK + m0 + tid];
        }
        __syncthreads();

        const int rAL0 = ALb * 8 + crow, rAL1 = rAL0 + 8;
        const int rAH0 = AHb * 8 + crow, rAH1 = rAH0 + 8;
        const int tAL0 = s_tok[rAL0], tAL1 = s_tok[rAL1];
        const int tAH0 = s_tok[rAH0], tAH1 = s_tok[rAH1];
        const u16* gAL0 = xb + (size_t)(tAL0 >> 2) * DH + gsw;
        const u16* gAL1 = xb + (size_t)(tAL1 >> 2) * DH + gsw;
        const u16* gAH0 = xb + (size_t)(tAH0 >> 2) * DH + gsw;
        const u16* gAH1 = xb + (size_t)(tAH1 >> 2) * DH + gsw;
        const u16* wbe  = wbt + ((size_t)e << 20);
        const u16* gBL0 = wbe + (size_t)(n0 + BLb * 8 + crow) * DH + gsw;
        const u16* gBL1 = gBL0 + (size_t)8 * DH;
        const u16* gBH0 = wbe + (size_t)(n0 + BHb * 8 + crow) * DH + gsw;
        const u16* gBH1 = gBH0 + (size_t)8 * DH;

        f32x4 acc[8][4] = {};

        #pragma unroll
        for (int kt = 0; kt < 2; kt++) {
            const int ko = kt * 64; const int p = kt;
            glds16(gAL0 + ko, &As[p][ALb * 512]); glds16(gAL1 + ko, &As[p][(ALb + 1) * 512]);
            glds16(gAH0 + ko, &As[p][AHb * 512]); glds16(gAH1 + ko, &As[p][(AHb + 1) * 512]);
            glds16(gBL0 + ko, &Bs[p][BLb * 512]); glds16(gBL1 + ko, &Bs[p][(BLb + 1) * 512]);
            glds16(gBH0 + ko, &Bs[p][BHb * 512]); glds16(gBH1 + ko, &Bs[p][(BHb + 1) * 512]);
        }
        WAITVM(8);            // tile 0 resident (tile 1 in flight)
        SBAR();

        const int arow = (wr * 128 + fr) * 64;    // u16 base of this lane's A frag rows
        const int brow = (wc * 64  + fr) * 64;
        const int c0 = fq ^ swz;                  // k-half 0 column (u16)
        const int c1 = (32 + fq) ^ swz;           // k-half 1 column

        bf16x8 afL[4][2], afH[4][2], bfL[2][2], bfH[2][2];

        for (int kt = 0; kt < 16; ++kt) {
            const int p = kt & 1;
            const u16* Ap = &As[p][0];
            const u16* Bp = &Bs[p][0];

            // ---- P1: read afL(8)+bfL(4); stage A-H of kt+1 -> buf p^1; MFMA miL x njL ----
            #pragma unroll
            for (int mi = 0; mi < 4; mi++) {
                afL[mi][0] = *(const bf16x8*)&Ap[arow + mi * 1024 + c0];
                afL[mi][1] = *(const bf16x8*)&Ap[arow + mi * 1024 + c1];
            }
            #pragma unroll
            for (int nj = 0; nj < 2; nj++) {
                bfL[nj][0] = *(const bf16x8*)&Bp[brow + nj * 1024 + c0];
                bfL[nj][1] = *(const bf16x8*)&Bp[brow + nj * 1024 + c1];
            }
            if (kt >= 1 && kt <= 14) {             // A-H rows of p^1 died at end-P3 of kt-1
                const int ko = (kt + 1) * 64; const int q = (kt + 1) & 1;
                glds16(gAH0 + ko, &As[q][AHb * 512]);
                glds16(gAH1 + ko, &As[q][(AHb + 1) * 512]);
            }
            asm volatile("s_waitcnt lgkmcnt(8)" ::: "memory");   // 12-read phase hint (template)
            SBAR(); WAITLGKM0();
            __builtin_amdgcn_s_setprio(1);
            #pragma unroll
            for (int mi = 0; mi < 4; mi++)
                #pragma unroll
                for (int nj = 0; nj < 2; nj++) {
                    acc[mi][nj] = __builtin_amdgcn_mfma_f32_16x16x32_bf16(afL[mi][0], bfL[nj][0], acc[mi][nj], 0, 0, 0);
                    acc[mi][nj] = __builtin_amdgcn_mfma_f32_16x16x32_bf16(afL[mi][1], bfL[nj][1], acc[mi][nj], 0, 0, 0);
                }
            __builtin_amdgcn_s_setprio(0);
            SBAR();                                // A-L/B-L rows of buf p now dead

            // ---- P2: read bfH(4); stage A-L of kt+2 -> buf p; MFMA miL x njH ----
            #pragma unroll
            for (int nj = 0; nj < 2; nj++) {
                bfH[nj][0] = *(const bf16x8*)&Bp[brow + (nj + 2) * 1024 + c0];
                bfH[nj][1] = *(const bf16x8*)&Bp[brow + (nj + 2) * 1024 + c1];
            }
            if (kt <= 13) {
                const int ko = (kt + 2) * 64;
                glds16(gAL0 + ko, &As[p][ALb * 512]);
                glds16(gAL1 + ko, &As[p][(ALb + 1) * 512]);
            }
            SBAR(); WAITLGKM0();
            __builtin_amdgcn_s_setprio(1);
            #pragma unroll
            for (int mi = 0; mi < 4; mi++)
                #pragma unroll
                for (int nj = 0; nj < 2; nj++) {
                    acc[mi][nj + 2] = __builtin_amdgcn_mfma_f32_16x16x32_bf16(afL[mi][0], bfH[nj][0], acc[mi][nj + 2], 0, 0, 0);
                    acc[mi][nj + 2] = __builtin_amdgcn_mfma_f32_16x16x32_bf16(afL[mi][1], bfH[nj][1], acc[mi][nj + 2], 0, 0, 0);
                }
            __builtin_amdgcn_s_setprio(0);
            SBAR();                                // B-H rows of buf p now dead

            // ---- P3: read afH(8); stage B-L of kt+2 -> buf p; MFMA miH x njH ----
            #pragma unroll
            for (int mi = 0; mi < 4; mi++) {
                afH[mi][0] = *(const bf16x8*)&Ap[arow + (mi + 4) * 1024 + c0];
                afH[mi][1] = *(const bf16x8*)&Ap[arow + (mi + 4) * 1024 + c1];
            }
            if (kt <= 13) {
                const int ko = (kt + 2) * 64;
                glds16(gBL0 + ko, &Bs[p][BLb * 512]);
                glds16(gBL1 + ko, &Bs[p][(BLb + 1) * 512]);
            }
            SBAR(); WAITLGKM0();
            __builtin_amdgcn_s_setprio(1);
            #pragma unroll
            for (int mi = 0; mi < 4; mi++)
                #pragma unroll
                for (int nj = 0; nj < 2; nj++) {
                    acc[mi + 4][nj + 2] = __builtin_amdgcn_mfma_f32_16x16x32_bf16(afH[mi][0], bfH[nj][0], acc[mi + 4][nj + 2], 0, 0, 0);
                    acc[mi + 4][nj + 2] = __builtin_amdgcn_mfma_f32_16x16x32_bf16(afH[mi][1], bfH[nj][1], acc[mi + 4][nj + 2], 0, 0, 0);
                }
            __builtin_amdgcn_s_setprio(0);
            SBAR();                                // A-H rows of buf p now dead

            // ---- P4: stage B-H of kt+2 -> buf p; MFMA miH x njL (regs only); counted vmcnt ----
            if (kt <= 13) {
                const int ko = (kt + 2) * 64;
                glds16(gBH0 + ko, &Bs[p][BHb * 512]);
                glds16(gBH1 + ko, &Bs[p][(BHb + 1) * 512]);
            }
            __builtin_amdgcn_s_setprio(1);
            #pragma unroll
            for (int mi = 0; mi < 4; mi++)
                #pragma unroll
                for (int nj = 0; nj < 2; nj++) {
                    acc[mi + 4][nj] = __builtin_amdgcn_mfma_f32_16x16x32_bf16(afH[mi][0], bfL[nj][0], acc[mi + 4][nj], 0, 0, 0);
                    acc[mi + 4][nj] = __builtin_amdgcn_mfma_f32_16x16x32_bf16(afH[mi][1], bfL[nj][1], acc[mi + 4][nj], 0, 0, 0);
                }
            __builtin_amdgcn_s_setprio(0);
            // newer-than-(kt+1) loads = kt+2's A-L,B-L,B-H = 6 -> vmcnt(6) => tile kt+1 resident
            if (kt <= 13)      WAITVM(6);
            else if (kt == 14) WAITVM(0);          // drain for tile 15
            SBAR();
        }

        // C/D layout: col = lane&15, row = (lane>>4)*4 + r
        const int cl = lane & 15;
        const int rb = (lane >> 4) * 4;
        #pragma unroll
        for (int mi = 0; mi < 8; mi++) {
            #pragma unroll
            for (int r = 0; r < 4; r++) {
                const int srow = wr * 128 + mi * 16 + rb + r;
                const int tok = s_tok[srow];
                const float w = s_w[srow];
                u16* yr = y + (size_t)tok * DH + (n0 + wc * 64 + cl);
                #pragma unroll
                for (int nj = 0; nj < 4; nj++)
                    yr[nj * 16] = f2b(acc[mi][nj][r] * w);
            }
        }
    }
}

// ---------------- tail GEMM: remainder rows [floor(M/256)*256, M) per expert ----------------
__global__ __launch_bounds__(512) void moe_gemm_tail_kernel(
    const u16* __restrict__ xb, const u16* __restrict__ wbt,
    const int* __restrict__ bucket_tok, const float* __restrict__ bucket_w,
    const int* __restrict__ cnt, u16* __restrict__ y)
{
    __shared__ u16 As[2][64 * 64];    // 16 KB
    __shared__ u16 Bs[2][256 * 64];   // 64 KB
    __shared__ int   s_tok[64];
    __shared__ float s_w[64];

    const int e  = blockIdx.z;
    const int sb = blockIdx.y;         // 0..3: 64-row sub-tile of the remainder
    const int nb = blockIdx.x;         // 0..3: 256-col block
    const int M  = cnt[e];
    const int m0 = ((M >> 8) << 8) + sb * 64;
    if (m0 >= M) return;
    const int n0 = nb << 8;

    const int tid  = threadIdx.x;
    const int lane = tid & 63;
    const int w8   = tid >> 6;         // 0..7: col group (32 cols each)
    const int fr   = lane & 15;
    const int fq   = (lane >> 4) * 8;
    const int swz  = (fr & 7) << 3;
    const int gsw  = ((lane & 7) ^ (lane >> 3)) * 8;
    const int crow = lane >> 3;

    if (tid < 64) {
        const int slot = m0 + tid;
        if (slot < M) { s_tok[tid] = bucket_tok[e * T_TOK + slot]; s_w[tid] = bucket_w[e * T_TOK + slot]; }
        else          { s_tok[tid] = -1;                           s_w[tid] = 0.f; }
    }
    __syncthreads();

    const int tA = s_tok[w8 * 8 + crow];
    const u16* gA = xb + (size_t)(tA >= 0 ? (tA >> 2) : 0) * DH + gsw;
    const u16* wbe = wbt + ((size_t)e << 20);
    const u16* gB0 = wbe + (size_t)(n0 + (4 * w8 + 0) * 8 + crow) * DH + gsw;
    const u16* gB1 = wbe + (size_t)(n0 + (4 * w8 + 1) * 8 + crow) * DH + gsw;
    const u16* gB2 = wbe + (size_t)(n0 + (4 * w8 + 2) * 8 + crow) * DH + gsw;
    const u16* gB3 = wbe + (size_t)(n0 + (4 * w8 + 3) * 8 + crow) * DH + gsw;

    f32x4 acc[4][2] = {};

    #define TSTAGE(kt) do { const int p_ = (kt) & 1; const int ko_ = (kt) * 64;         \
        glds16(gA  + ko_, &As[p_][w8 * 512]);                                           \
        glds16(gB0 + ko_, &Bs[p_][(4 * w8 + 0) * 512]);                                 \
        glds16(gB1 + ko_, &Bs[p_][(4 * w8 + 1) * 512]);                                 \
        glds16(gB2 + ko_, &Bs[p_][(4 * w8 + 2) * 512]);                                 \
        glds16(gB3 + ko_, &Bs[p_][(4 * w8 + 3) * 512]); } while (0)

    TSTAGE(0); TSTAGE(1);              // 10 in flight per wave
    WAITVM(5);                         // tile 0 resident
    SBAR();

    const int c0 = fq ^ swz;
    const int c1 = (32 + fq) ^ swz;

    for (int kt = 0; kt < 16; ++kt) {
        const int p = kt & 1;
        bf16x8 af[4][2], bf[2][2];
        #pragma unroll
        for (int mi = 0; mi < 4; mi++) {
            af[mi][0] = *(const bf16x8*)&As[p][(mi * 16 + fr) * 64 + c0];
            af[mi][1] = *(const bf16x8*)&As[p][(mi * 16 + fr) * 64 + c1];
        }
        #pragma unroll
        for (int nj = 0; nj < 2; nj++) {
            bf[nj][0] = *(const bf16x8*)&Bs[p][(w8 * 32 + nj * 16 + fr) * 64 + c0];
            bf[nj][1] = *(const bf16x8*)&Bs[p][(w8 * 32 + nj * 16 + fr) * 64 + c1];
        }
        WAITLGKM0();
        __builtin_amdgcn_s_setprio(1);
        #pragma unroll
        for (int mi = 0; mi < 4; mi++)
            #pragma unroll
            for (int nj = 0; nj < 2; nj++) {
                acc[mi][nj] = __builtin_amdgcn_mfma_f32_16x16x32_bf16(af[mi][0], bf[nj][0], acc[mi][nj], 0, 0, 0);
                acc[mi][nj] = __builtin_amdgcn_mfma_f32_16x16x32_bf16(af[mi][1], bf[nj][1], acc[mi][nj], 0, 0, 0);
            }
        __builtin_amdgcn_s_setprio(0);
        SBAR();                        // all waves done reading buf p
        if (kt + 2 < 16) { TSTAGE(kt + 2); WAITVM(5); }   // tile kt+1 resident
        else if (kt == 14) WAITVM(0);                     // drain for tile 15
        if (kt < 15) SBAR();
    }
    #undef TSTAGE

    // C/D layout: col = lane&15, row = (lane>>4)*4 + r
    const int cl = lane & 15;
    const int rb = (lane >> 4) * 4;
    #pragma unroll
    for (int mi = 0; mi < 4; mi++) {
        #pragma unroll
        for (int r = 0; r < 4; r++) {
            const int srow = mi * 16 + rb + r;
            const int tok = s_tok[srow];
            if (tok < 0) continue;
            const float w = s_w[srow];
            u16* yr = y + (size_t)tok * DH + (n0 + w8 * 32 + cl);
            #pragma unroll
            for (int nj = 0; nj < 2; nj++)
                yr[nj * 16] = f2b(acc[mi][nj][r] * w);
        }
    }
}

// ---------------- combine: out[t] = sum_k y[t*4+k] + sum_k w_k*b[e_k]; block 0 does aux ----------------
__global__ __launch_bounds__(256) void combine_kernel(
    const u16* __restrict__ y, const int* __restrict__ tk_e, const float* __restrict__ tk_w,
    const float* __restrict__ bexp,
    const int* __restrict__ cnt, const float* __restrict__ probsum,
    float* __restrict__ out, float* __restrict__ out_aux)
{
    if (blockIdx.x == 0 && threadIdx.x == 0) {
        float s = 0.f;
        for (int e = 0; e < NE; e++) s += (float)cnt[e] * probsum[e];
        out_aux[0] = s * (float)NE / ((float)T_TOK * (float)T_TOK);
    }
    const int t = blockIdx.x * 2 + (threadIdx.x >> 7);
    const int c = (threadIdx.x & 127) * 8;
    float o[8] = {};
    #pragma unroll
    for (int k = 0; k < TK; k++) {
        const int e   = tk_e[t * TK + k];
        const float w = tk_w[t * TK + k];
        const u16* yp = y + ((size_t)(t * TK + k)) * DH + c;
        const ushort4 y0 = *(const ushort4*)(yp);
        const ushort4 y1 = *(const ushort4*)(yp + 4);
        const float4  b0 = *(const float4*)(bexp + (size_t)e * DH + c);
        const float4  b1 = *(const float4*)(bexp + (size_t)e * DH + c + 4);
        o[0] += b2f(y0.x) + w * b0.x;
        o[1] += b2f(y0.y) + w * b0.y;
        o[2] += b2f(y0.z) + w * b0.z;
        o[3] += b2f(y0.w) + w * b0.w;
        o[4] += b2f(y1.x) + w * b1.x;
        o[5] += b2f(y1.y) + w * b1.y;
        o[6] += b2f(y1.z) + w * b1.z;
        o[7] += b2f(y1.w) + w * b1.w;
    }
    float4 ov0 = {o[0], o[1], o[2], o[3]};
    float4 ov1 = {o[4], o[5], o[6], o[7]};
    *(float4*)(out + (size_t)t * DH + c)     = ov0;
    *(float4*)(out + (size_t)t * DH + c + 4) = ov1;
}

extern "C" void kernel_launch(void* const* d_in, const int* in_sizes, int n_in,
                              void* d_out, int out_size, void* d_ws, size_t ws_size,
                              hipStream_t stream)
{
    const float* x  = (const float*)d_in[0];
    const float* Wg = (const float*)d_in[1];
    const float* bg = (const float*)d_in[2];
    const float* W  = (const float*)d_in[3];
    const float* b  = (const float*)d_in[4];
    float* out = (float*)d_out;

    char* ws = (char*)d_ws;
    u16*   xb         = (u16*)(ws);                    // 16,777,216 B
    u16*   wbt        = (u16*)(ws + 16777216);         // 16,777,216 B
    u16*   y          = (u16*)(ws + 33554432);         // 67,108,864 B
    int*   bucket_tok = (int*)(ws + 100663296);        //    262,144 B
    float* bucket_w   = (float*)(ws + 100925440);      //    262,144 B
    int*   tk_e       = (int*)(ws + 101187584);        //    131,072 B
    float* tk_w       = (float*)(ws + 101318656);      //    131,072 B
    int*   cnt        = (int*)(ws + 101449728);        //         32 B
    float* probsum    = (float*)(ws + 101449760);      //         32 B

    hipMemsetAsync(cnt, 0, 64, stream);  // cnt + probsum (must precede router atomics)

    prep_kernel<<<2048, 512, 0, stream>>>(W, wbt, x, Wg, bg, xb,
                                          bucket_tok, bucket_w, tk_e, tk_w, cnt, probsum);
    moe_gemm_kernel<<<dim3(256), 512, 0, stream>>>(xb, wbt, bucket_tok, bucket_w, cnt, y);
    moe_gemm_tail_kernel<<<dim3(4, 4, NE), 512, 0, stream>>>(xb, wbt, bucket_tok, bucket_w, cnt, y);
    combine_kernel<<<4096, 256, 0, stream>>>(y, tk_e, tk_w, b, cnt, probsum, out, out + (size_t)T_TOK * DH);
}

// Round 12
// 248.010 us; speedup vs baseline: 1.0736x; 1.0010x over previous
//
#include <hip/hip_runtime.h>
#include <hip/hip_bf16.h>

#define T_TOK 8192
#define DH    1024
#define NE    8
#define TK    4

typedef unsigned short u16;
typedef __bf16 bf16x8 __attribute__((ext_vector_type(8)));
typedef float  f32x4  __attribute__((ext_vector_type(4)));

__device__ __forceinline__ u16 f2b(float f) {
    union { float f; unsigned u; } v; v.f = f;
    unsigned u = v.u;
    u += 0x7FFFu + ((u >> 16) & 1u);   // round-to-nearest-even
    return (u16)(u >> 16);
}
__device__ __forceinline__ float b2f(u16 h) {
    union { unsigned u; float f; } v; v.u = ((unsigned)h) << 16;
    return v.f;
}
// async global->LDS, 16B per lane; LDS dest = wave-uniform base + lane*16 (linear!)
__device__ __forceinline__ void glds16(const u16* g, u16* l) {
    __builtin_amdgcn_global_load_lds((const __attribute__((address_space(1))) void*)g,
                                     (__attribute__((address_space(3))) void*)l, 16, 0, 0);
}

#define FENCE() asm volatile("" ::: "memory")
#define SBAR()  do { FENCE(); __builtin_amdgcn_s_barrier(); FENCE(); } while (0)
// rule 18: hipcc can hoist reg-only MFMA past an inline-asm lgkmcnt; fence with sched_barrier(0)
#define WAITLGKM0() do { asm volatile("s_waitcnt lgkmcnt(0)" ::: "memory"); \
                         __builtin_amdgcn_sched_barrier(0); } while (0)
#define WAITVM(n) asm volatile("s_waitcnt vmcnt(" #n ")" ::: "memory")

// ---------------- fused prep: cast W (blocks 0..1023, 2 tiles each) + router (1024..2047) ----------------
__global__ __launch_bounds__(512) void prep_kernel(
    const float* __restrict__ W, u16* __restrict__ wbt,
    const float* __restrict__ x, const float* __restrict__ Wg, const float* __restrict__ bg,
    u16* __restrict__ xb,
    int* __restrict__ bucket_tok, float* __restrict__ bucket_w,
    int* __restrict__ tk_e, float* __restrict__ tk_w,
    int* __restrict__ cnt, float* __restrict__ probsum)
{
    __shared__ float tile2[2][64][65];   // cast path (33.3 KB)
    __shared__ int   lcnt[NE];
    __shared__ float lprob[NE];
    __shared__ int   gbase[NE];

    const int bid = blockIdx.x;
    const int tid = threadIdx.x;

    if (bid < 1024) {
        // ------- cast W -> bf16, transposed to [e][f][d]; two 64x64 tiles per block -------
        const int half = tid >> 8;            // 0..1
        const int tloc = tid & 255;
        const int r  = tloc >> 4;             // 0..15
        const int c4 = (tloc & 15) * 4;       // 0,4,...,60
        float (*tile)[65] = tile2[half];
        const int jc = bid * 2 + half;        // 0..2047
        const int f0 = (jc & 15) * 64;
        const int d0 = ((jc >> 4) & 15) * 64;
        const int e  = jc >> 8;
        const float* src = W + ((size_t)e << 20) + (size_t)d0 * DH + f0;
        #pragma unroll
        for (int i = 0; i < 4; i++) {
            const int row = i * 16 + r;
            const float4 v = *(const float4*)(src + (size_t)row * DH + c4);
            tile[row][c4]     = v.x;
            tile[row][c4 + 1] = v.y;
            tile[row][c4 + 2] = v.z;
            tile[row][c4 + 3] = v.w;
        }
        __syncthreads();
        u16* dst = wbt + ((size_t)e << 20) + (size_t)f0 * DH + d0;
        #pragma unroll
        for (int i = 0; i < 4; i++) {
            const int orow = i * 16 + r;      // f-index within tile
            ushort4 o;
            o.x = f2b(tile[c4][orow]);
            o.y = f2b(tile[c4 + 1][orow]);
            o.z = f2b(tile[c4 + 2][orow]);
            o.w = f2b(tile[c4 + 3][orow]);
            *(ushort4*)(dst + (size_t)orow * DH + c4) = o;
        }
        return;
    }

    // ------- router: logits + softmax + top4 + buckets, fused x->bf16 cast -------
    const int wv = tid >> 6, lane = tid & 63;
    const int t = (bid - 1024) * 8 + wv;
    if (tid < NE) { lcnt[tid] = 0; lprob[tid] = 0.f; }
    __syncthreads();

    float a[NE] = {};
    {
        const float* xr = x + (size_t)t * DH;
        u16* xbr = xb + (size_t)t * DH;
        const float4* wg = (const float4*)Wg;   // row d -> wg[2d] (e0..3), wg[2d+1] (e4..7)
        #pragma unroll
        for (int it = 0; it < 4; it++) {
            const int d = it * 256 + lane * 4;
            const float4 v = *(const float4*)(xr + d);
            ushort4 o;
            o.x = f2b(v.x); o.y = f2b(v.y); o.z = f2b(v.z); o.w = f2b(v.w);
            *(ushort4*)(xbr + d) = o;
            const float4 w0l = wg[2 * (d + 0)], w0h = wg[2 * (d + 0) + 1];
            const float4 w1l = wg[2 * (d + 1)], w1h = wg[2 * (d + 1) + 1];
            const float4 w2l = wg[2 * (d + 2)], w2h = wg[2 * (d + 2) + 1];
            const float4 w3l = wg[2 * (d + 3)], w3h = wg[2 * (d + 3) + 1];
            a[0] += v.x * w0l.x + v.y * w1l.x + v.z * w2l.x + v.w * w3l.x;
            a[1] += v.x * w0l.y + v.y * w1l.y + v.z * w2l.y + v.w * w3l.y;
            a[2] += v.x * w0l.z + v.y * w1l.z + v.z * w2l.z + v.w * w3l.z;
            a[3] += v.x * w0l.w + v.y * w1l.w + v.z * w2l.w + v.w * w3l.w;
            a[4] += v.x * w0h.x + v.y * w1h.x + v.z * w2h.x + v.w * w3h.x;
            a[5] += v.x * w0h.y + v.y * w1h.y + v.z * w2h.y + v.w * w3h.y;
            a[6] += v.x * w0h.z + v.y * w1h.z + v.z * w2h.z + v.w * w3h.z;
            a[7] += v.x * w0h.w + v.y * w1h.w + v.z * w2h.w + v.w * w3h.w;
        }
    }
    #pragma unroll
    for (int e = 0; e < NE; e++) {
        float v = a[e];
        #pragma unroll
        for (int off = 32; off > 0; off >>= 1) v += __shfl_down(v, off);
        a[e] = v;
    }

    int idx4[TK]; float w4[TK]; int off4[TK];
    if (lane == 0) {
        float logits[NE], probs[NE];
        float mx = -1e30f;
        #pragma unroll
        for (int e = 0; e < NE; e++) { logits[e] = a[e] + bg[e]; mx = fmaxf(mx, logits[e]); }
        float Z = 0.f;
        #pragma unroll
        for (int e = 0; e < NE; e++) { probs[e] = expf(logits[e] - mx); Z += probs[e]; }
        const float rZ = 1.f / Z;
        #pragma unroll
        for (int e = 0; e < NE; e++) probs[e] *= rZ;

        float rem2[NE];
        #pragma unroll
        for (int e = 0; e < NE; e++) rem2[e] = probs[e];
        float s4 = 0.f;
        #pragma unroll
        for (int k = 0; k < TK; k++) {   // strict > scan from 0 == jax tie-break (lowest idx)
            int best = 0; float bv = rem2[0];
            #pragma unroll
            for (int e = 1; e < NE; e++) if (rem2[e] > bv) { bv = rem2[e]; best = e; }
            idx4[k] = best; w4[k] = bv; s4 += bv; rem2[best] = -1e30f;
        }
        const float rs = 1.f / (s4 + 1e-6f);
        #pragma unroll
        for (int k = 0; k < TK; k++) {
            w4[k] *= rs;
            tk_e[t * TK + k] = idx4[k];
            tk_w[t * TK + k] = w4[k];
            off4[k] = atomicAdd(&lcnt[idx4[k]], 1);
        }
        #pragma unroll
        for (int e = 0; e < NE; e++) atomicAdd(&lprob[e], probs[e]);
    }
    __syncthreads();
    if (tid < NE) {
        gbase[tid] = atomicAdd(&cnt[tid], lcnt[tid]);
        atomicAdd(&probsum[tid], lprob[tid]);
    }
    __syncthreads();
    if (lane == 0) {
        #pragma unroll
        for (int k = 0; k < TK; k++) {
            const int e = idx4[k];
            const int slot = gbase[e] + off4[k];
            bucket_tok[e * T_TOK + slot] = (t << 2) | k;
            bucket_w[e * T_TOK + slot]   = w4[k];
        }
    }
}

// ---------------- grouped gather GEMM, 256x256 / BK=64 / 8-wave / 4-phase-per-K-tile ----------------
// R12 = R11 inner loop VERBATIM; schedule = EXPERT-ALIGNED slot map (affinity + balance):
//  - R9 had affinity (FETCH 48MB) but makespan 2.45; R11 had makespan 2.0 but lost
//    affinity (FETCH 79MB, per-unit 35.8->40.2us). Separable -> get both.
//  - XCD x, slot s (= 2c+u of block c): s < min(nt[x],64) -> expert x's tile s (HOME,
//    ~97% of tiles). Else: residual pairing of deficit slots (XCD-major) with leftover
//    tiles of heavy experts (expert-major) via two 8-entry prefix lists; <=~10 chip-wide.
//  - Sum nt <= 512 always (sum M_e = 32768) -> makespan exactly 2 units.
//  - Slot pair (2c,2c+1) shares mb (t even -> t,t+1 share t>>2) -> A-panel reuse.
//  - All block-uniform SGPR math from cnt; inner loop/staging/waits byte-identical.
__global__ __launch_bounds__(512, 2) void moe_gemm_kernel(
    const u16* __restrict__ xb, const u16* __restrict__ wbt,
    const int* __restrict__ bucket_tok, const float* __restrict__ bucket_w,
    const int* __restrict__ cnt, u16* __restrict__ y)
{
    __shared__ u16 As[2][256 * 64];   // 64 KB
    __shared__ u16 Bs[2][256 * 64];   // 64 KB
    __shared__ int   s_tok[256];
    __shared__ float s_w[256];

    const int tid  = threadIdx.x;
    const int lane = tid & 63;
    const int wid  = tid >> 6;            // 0..7
    const int wr   = wid >> 2;            // 0..1 (M)
    const int wc   = wid & 3;             // 0..3 (N)
    const int fr   = lane & 15;
    const int fq   = (lane >> 4) * 8;
    const int swz  = (fr & 7) << 3;       // u16-index XOR for frag reads
    const int gsw  = ((lane & 7) ^ (lane >> 3)) * 8;  // pre-swizzled global u16 col for staging
    const int crow = lane >> 3;           // row within 8-row chunk

    const int ALb = 2 * wid + (wid >= 4 ? 8 : 0);
    const int AHb = ALb + 8;
    const int BLb = (wid >> 1) * 8 + (wid & 1) * 2;
    const int BHb = BLb + 4;

    // expert-aligned slot map (block-uniform)
    int nt[NE];
    #pragma unroll
    for (int e = 0; e < NE; e++) nt[e] = (cnt[e] >> 8) << 2;   // full tiles per expert
    int dpfx[NE + 1], lpfx[NE + 1];
    dpfx[0] = 0; lpfx[0] = 0;
    #pragma unroll
    for (int e = 0; e < NE; e++) {
        const int own = nt[e] < 64 ? nt[e] : 64;
        dpfx[e + 1] = dpfx[e] + (64 - own);       // deficit slots, XCD-major
        lpfx[e + 1] = lpfx[e] + (nt[e] - own);    // leftover tiles, expert-major
    }
    const int xcd = blockIdx.x & 7;
    const int cc  = blockIdx.x >> 3;              // 0..31 within XCD
    const int ownx = nt[xcd] < 64 ? nt[xcd] : 64;

    for (int u = 0; u < 2; ++u) {
        const int s = 2 * cc + u;                 // slot within this XCD
        int e, tt;
        if (s < ownx) { e = xcd; tt = s; }        // home tile
        else {
            const int d = dpfx[xcd] + (s - ownx); // global deficit index
            if (d >= lpfx[NE]) continue;          // idle slot (uniform)
            e = 0;
            #pragma unroll
            for (int k = 1; k < NE; k++) if (lpfx[k] <= d) e = k;
            tt = 64 + (d - lpfx[e]);              // leftover tile of heavy expert
        }
        const int m0 = (tt >> 2) << 8;
        const int n0 = (tt & 3) << 8;

        __syncthreads();                   // s_tok/s_w + LDS reuse across tiles
        if (tid < 256) {
            s_tok[tid] = bucket_tok[e * T_TOK + m0 + tid];
            s_w[tid]   = bucket_w[e * T_TOK + m0 + tid];
        }
        __syncthreads();

        const int rAL0 = ALb * 8 + crow, rAL1 = rAL0 + 8;
        const int rAH0 = AHb * 8 + crow, rAH1 = rAH0 + 8;
        const int tAL0 = s_tok[rAL0], tAL1 = s_tok[rAL1];
        const int tAH0 = s_tok[rAH0], tAH1 = s_tok[rAH1];
        const u16* gAL0 = xb + (size_t)(tAL0 >> 2) * DH + gsw;
        const u16* gAL1 = xb + (size_t)(tAL1 >> 2) * DH + gsw;
        const u16* gAH0 = xb + (size_t)(tAH0 >> 2) * DH + gsw;
        const u16* gAH1 = xb + (size_t)(tAH1 >> 2) * DH + gsw;
        const u16* wbe  = wbt + ((size_t)e << 20);
        const u16* gBL0 = wbe + (size_t)(n0 + BLb * 8 + crow) * DH + gsw;
        const u16* gBL1 = gBL0 + (size_t)8 * DH;
        const u16* gBH0 = wbe + (size_t)(n0 + BHb * 8 + crow) * DH + gsw;
        const u16* gBH1 = gBH0 + (size_t)8 * DH;

        f32x4 acc[8][4] = {};

        #pragma unroll
        for (int kt = 0; kt < 2; kt++) {
            const int ko = kt * 64; const int p = kt;
            glds16(gAL0 + ko, &As[p][ALb * 512]); glds16(gAL1 + ko, &As[p][(ALb + 1) * 512]);
            glds16(gAH0 + ko, &As[p][AHb * 512]); glds16(gAH1 + ko, &As[p][(AHb + 1) * 512]);
            glds16(gBL0 + ko, &Bs[p][BLb * 512]); glds16(gBL1 + ko, &Bs[p][(BLb + 1) * 512]);
            glds16(gBH0 + ko, &Bs[p][BHb * 512]); glds16(gBH1 + ko, &Bs[p][(BHb + 1) * 512]);
        }
        WAITVM(8);            // tile 0 resident (tile 1 in flight)
        SBAR();

        const int arow = (wr * 128 + fr) * 64;    // u16 base of this lane's A frag rows
        const int brow = (wc * 64  + fr) * 64;
        const int c0 = fq ^ swz;                  // k-half 0 column (u16)
        const int c1 = (32 + fq) ^ swz;           // k-half 1 column

        bf16x8 afL[4][2], afH[4][2], bfL[2][2], bfH[2][2];

        for (int kt = 0; kt < 16; ++kt) {
            const int p = kt & 1;
            const u16* Ap = &As[p][0];
            const u16* Bp = &Bs[p][0];

            // ---- P1: read afL(8)+bfL(4); stage A-H of kt+1 -> buf p^1; MFMA miL x njL ----
            #pragma unroll
            for (int mi = 0; mi < 4; mi++) {
                afL[mi][0] = *(const bf16x8*)&Ap[arow + mi * 1024 + c0];
                afL[mi][1] = *(const bf16x8*)&Ap[arow + mi * 1024 + c1];
            }
            #pragma unroll
            for (int nj = 0; nj < 2; nj++) {
                bfL[nj][0] = *(const bf16x8*)&Bp[brow + nj * 1024 + c0];
                bfL[nj][1] = *(const bf16x8*)&Bp[brow + nj * 1024 + c1];
            }
            if (kt >= 1 && kt <= 14) {             // A-H rows of p^1 died at end-P3 of kt-1
                const int ko = (kt + 1) * 64; const int q = (kt + 1) & 1;
                glds16(gAH0 + ko, &As[q][AHb * 512]);
                glds16(gAH1 + ko, &As[q][(AHb + 1) * 512]);
            }
            asm volatile("s_waitcnt lgkmcnt(8)" ::: "memory");   // 12-read phase hint (template)
            SBAR(); WAITLGKM0();
            __builtin_amdgcn_s_setprio(1);
            #pragma unroll
            for (int mi = 0; mi < 4; mi++)
                #pragma unroll
                for (int nj = 0; nj < 2; nj++) {
                    acc[mi][nj] = __builtin_amdgcn_mfma_f32_16x16x32_bf16(afL[mi][0], bfL[nj][0], acc[mi][nj], 0, 0, 0);
                    acc[mi][nj] = __builtin_amdgcn_mfma_f32_16x16x32_bf16(afL[mi][1], bfL[nj][1], acc[mi][nj], 0, 0, 0);
                }
            __builtin_amdgcn_s_setprio(0);
            SBAR();                                // A-L/B-L rows of buf p now dead

            // ---- P2: read bfH(4); stage A-L of kt+2 -> buf p; MFMA miL x njH ----
            #pragma unroll
            for (int nj = 0; nj < 2; nj++) {
                bfH[nj][0] = *(const bf16x8*)&Bp[brow + (nj + 2) * 1024 + c0];
                bfH[nj][1] = *(const bf16x8*)&Bp[brow + (nj + 2) * 1024 + c1];
            }
            if (kt <= 13) {
                const int ko = (kt + 2) * 64;
                glds16(gAL0 + ko, &As[p][ALb * 512]);
                glds16(gAL1 + ko, &As[p][(ALb + 1) * 512]);
            }
            SBAR(); WAITLGKM0();
            __builtin_amdgcn_s_setprio(1);
            #pragma unroll
            for (int mi = 0; mi < 4; mi++)
                #pragma unroll
                for (int nj = 0; nj < 2; nj++) {
                    acc[mi][nj + 2] = __builtin_amdgcn_mfma_f32_16x16x32_bf16(afL[mi][0], bfH[nj][0], acc[mi][nj + 2], 0, 0, 0);
                    acc[mi][nj + 2] = __builtin_amdgcn_mfma_f32_16x16x32_bf16(afL[mi][1], bfH[nj][1], acc[mi][nj + 2], 0, 0, 0);
                }
            __builtin_amdgcn_s_setprio(0);
            SBAR();                                // B-H rows of buf p now dead

            // ---- P3: read afH(8); stage B-L of kt+2 -> buf p; MFMA miH x njH ----
            #pragma unroll
            for (int mi = 0; mi < 4; mi++) {
                afH[mi][0] = *(const bf16x8*)&Ap[arow + (mi + 4) * 1024 + c0];
                afH[mi][1] = *(const bf16x8*)&Ap[arow + (mi + 4) * 1024 + c1];
            }
            if (kt <= 13) {
                const int ko = (kt + 2) * 64;
                glds16(gBL0 + ko, &Bs[p][BLb * 512]);
                glds16(gBL1 + ko, &Bs[p][(BLb + 1) * 512]);
            }
            SBAR(); WAITLGKM0();
            __builtin_amdgcn_s_setprio(1);
            #pragma unroll
            for (int mi = 0; mi < 4; mi++)
                #pragma unroll
                for (int nj = 0; nj < 2; nj++) {
                    acc[mi + 4][nj + 2] = __builtin_amdgcn_mfma_f32_16x16x32_bf16(afH[mi][0], bfH[nj][0], acc[mi + 4][nj + 2], 0, 0, 0);
                    acc[mi + 4][nj + 2] = __builtin_amdgcn_mfma_f32_16x16x32_bf16(afH[mi][1], bfH[nj][1], acc[mi + 4][nj + 2], 0, 0, 0);
                }
            __builtin_amdgcn_s_setprio(0);
            SBAR();                                // A-H rows of buf p now dead

            // ---- P4: stage B-H of kt+2 -> buf p; MFMA miH x njL (regs only); counted vmcnt ----
            if (kt <= 13) {
                const int ko = (kt + 2) * 64;
                glds16(gBH0 + ko, &Bs[p][BHb * 512]);
                glds16(gBH1 + ko, &Bs[p][(BHb + 1) * 512]);
            }
            __builtin_amdgcn_s_setprio(1);
            #pragma unroll
            for (int mi = 0; mi < 4; mi++)
                #pragma unroll
                for (int nj = 0; nj < 2; nj++) {
                    acc[mi + 4][nj] = __builtin_amdgcn_mfma_f32_16x16x32_bf16(afH[mi][0], bfL[nj][0], acc[mi + 4][nj], 0, 0, 0);
                    acc[mi + 4][nj] = __builtin_amdgcn_mfma_f32_16x16x32_bf16(afH[mi][1], bfL[nj][1], acc[mi + 4][nj], 0, 0, 0);
                }
            __builtin_amdgcn_s_setprio(0);
            // newer-than-(kt+1) loads = kt+2's A-L,B-L,B-H = 6 -> vmcnt(6) => tile kt+1 resident
            if (kt <= 13)      WAITVM(6);
            else if (kt == 14) WAITVM(0);          // drain for tile 15
            SBAR();
        }

        // C/D layout: col = lane&15, row = (lane>>4)*4 + r
        const int cl = lane & 15;
        const int rb = (lane >> 4) * 4;
        #pragma unroll
        for (int mi = 0; mi < 8; mi++) {
            #pragma unroll
            for (int r = 0; r < 4; r++) {
                const int srow = wr * 128 + mi * 16 + rb + r;
                const int tok = s_tok[srow];
                const float w = s_w[srow];
                u16* yr = y + (size_t)tok * DH + (n0 + wc * 64 + cl);
                #pragma unroll
                for (int nj = 0; nj < 4; nj++)
                    yr[nj * 16] = f2b(acc[mi][nj][r] * w);
            }
        }
    }
}

// ---------------- tail GEMM: remainder rows [floor(M/256)*256, M) per expert ----------------
__global__ __launch_bounds__(512) void moe_gemm_tail_kernel(
    const u16* __restrict__ xb, const u16* __restrict__ wbt,
    const int* __restrict__ bucket_tok, const float* __restrict__ bucket_w,
    const int* __restrict__ cnt, u16* __restrict__ y)
{
    __shared__ u16 As[2][64 * 64];    // 16 KB
    __shared__ u16 Bs[2][256 * 64];   // 64 KB
    __shared__ int   s_tok[64];
    __shared__ float s_w[64];

    const int e  = blockIdx.z;
    const int sb = blockIdx.y;         // 0..3: 64-row sub-tile of the remainder
    const int nb = blockIdx.x;         // 0..3: 256-col block
    const int M  = cnt[e];
    const int m0 = ((M >> 8) << 8) + sb * 64;
    if (m0 >= M) return;
    const int n0 = nb << 8;

    const int tid  = threadIdx.x;
    const int lane = tid & 63;
    const int w8   = tid >> 6;         // 0..7: col group (32 cols each)
    const int fr   = lane & 15;
    const int fq   = (lane >> 4) * 8;
    const int swz  = (fr & 7) << 3;
    const int gsw  = ((lane & 7) ^ (lane >> 3)) * 8;
    const int crow = lane >> 3;

    if (tid < 64) {
        const int slot = m0 + tid;
        if (slot < M) { s_tok[tid] = bucket_tok[e * T_TOK + slot]; s_w[tid] = bucket_w[e * T_TOK + slot]; }
        else          { s_tok[tid] = -1;                           s_w[tid] = 0.f; }
    }
    __syncthreads();

    const int tA = s_tok[w8 * 8 + crow];
    const u16* gA = xb + (size_t)(tA >= 0 ? (tA >> 2) : 0) * DH + gsw;
    const u16* wbe = wbt + ((size_t)e << 20);
    const u16* gB0 = wbe + (size_t)(n0 + (4 * w8 + 0) * 8 + crow) * DH + gsw;
    const u16* gB1 = wbe + (size_t)(n0 + (4 * w8 + 1) * 8 + crow) * DH + gsw;
    const u16* gB2 = wbe + (size_t)(n0 + (4 * w8 + 2) * 8 + crow) * DH + gsw;
    const u16* gB3 = wbe + (size_t)(n0 + (4 * w8 + 3) * 8 + crow) * DH + gsw;

    f32x4 acc[4][2] = {};

    #define TSTAGE(kt) do { const int p_ = (kt) & 1; const int ko_ = (kt) * 64;         \
        glds16(gA  + ko_, &As[p_][w8 * 512]);                                           \
        glds16(gB0 + ko_, &Bs[p_][(4 * w8 + 0) * 512]);                                 \
        glds16(gB1 + ko_, &Bs[p_][(4 * w8 + 1) * 512]);                                 \
        glds16(gB2 + ko_, &Bs[p_][(4 * w8 + 2) * 512]);                                 \
        glds16(gB3 + ko_, &Bs[p_][(4 * w8 + 3) * 512]); } while (0)

    TSTAGE(0); TSTAGE(1);              // 10 in flight per wave
    WAITVM(5);                         // tile 0 resident
    SBAR();

    const int c0 = fq ^ swz;
    const int c1 = (32 + fq) ^ swz;

    for (int kt = 0; kt < 16; ++kt) {
        const int p = kt & 1;
        bf16x8 af[4][2], bf[2][2];
        #pragma unroll
        for (int mi = 0; mi < 4; mi++) {
            af[mi][0] = *(const bf16x8*)&As[p][(mi * 16 + fr) * 64 + c0];
            af[mi][1] = *(const bf16x8*)&As[p][(mi * 16 + fr) * 64 + c1];
        }
        #pragma unroll
        for (int nj = 0; nj < 2; nj++) {
            bf[nj][0] = *(const bf16x8*)&Bs[p][(w8 * 32 + nj * 16 + fr) * 64 + c0];
            bf[nj][1] = *(const bf16x8*)&Bs[p][(w8 * 32 + nj * 16 + fr) * 64 + c1];
        }
        WAITLGKM0();
        __builtin_amdgcn_s_setprio(1);
        #pragma unroll
        for (int mi = 0; mi < 4; mi++)
            #pragma unroll
            for (int nj = 0; nj < 2; nj++) {
                acc[mi][nj] = __builtin_amdgcn_mfma_f32_16x16x32_bf16(af[mi][0], bf[nj][0], acc[mi][nj], 0, 0, 0);
                acc[mi][nj] = __builtin_amdgcn_mfma_f32_16x16x32_bf16(af[mi][1], bf[nj][1], acc[mi][nj], 0, 0, 0);
            }
        __builtin_amdgcn_s_setprio(0);
        SBAR();                        // all waves done reading buf p
        if (kt + 2 < 16) { TSTAGE(kt + 2); WAITVM(5); }   // tile kt+1 resident
        else if (kt == 14) WAITVM(0);                     // drain for tile 15
        if (kt < 15) SBAR();
    }
    #undef TSTAGE

    // C/D layout: col = lane&15, row = (lane>>4)*4 + r
    const int cl = lane & 15;
    const int rb = (lane >> 4) * 4;
    #pragma unroll
    for (int mi = 0; mi < 4; mi++) {
        #pragma unroll
        for (int r = 0; r < 4; r++) {
            const int srow = mi * 16 + rb + r;
            const int tok = s_tok[srow];
            if (tok < 0) continue;
            const float w = s_w[srow];
            u16* yr = y + (size_t)tok * DH + (n0 + w8 * 32 + cl);
            #pragma unroll
            for (int nj = 0; nj < 2; nj++)
                yr[nj * 16] = f2b(acc[mi][nj][r] * w);
        }
    }
}

// ---------------- combine: out[t] = sum_k y[t*4+k] + sum_k w_k*b[e_k]; block 0 does aux ----------------
__global__ __launch_bounds__(256) void combine_kernel(
    const u16* __restrict__ y, const int* __restrict__ tk_e, const float* __restrict__ tk_w,
    const float* __restrict__ bexp,
    const int* __restrict__ cnt, const float* __restrict__ probsum,
    float* __restrict__ out, float* __restrict__ out_aux)
{
    if (blockIdx.x == 0 && threadIdx.x == 0) {
        float s = 0.f;
        for (int e = 0; e < NE; e++) s += (float)cnt[e] * probsum[e];
        out_aux[0] = s * (float)NE / ((float)T_TOK * (float)T_TOK);
    }
    const int t = blockIdx.x * 2 + (threadIdx.x >> 7);
    const int c = (threadIdx.x & 127) * 8;
    float o[8] = {};
    #pragma unroll
    for (int k = 0; k < TK; k++) {
        const int e   = tk_e[t * TK + k];
        const float w = tk_w[t * TK + k];
        const u16* yp = y + ((size_t)(t * TK + k)) * DH + c;
        const ushort4 y0 = *(const ushort4*)(yp);
        const ushort4 y1 = *(const ushort4*)(yp + 4);
        const float4  b0 = *(const float4*)(bexp + (size_t)e * DH + c);
        const float4  b1 = *(const float4*)(bexp + (size_t)e * DH + c + 4);
        o[0] += b2f(y0.x) + w * b0.x;
        o[1] += b2f(y0.y) + w * b0.y;
        o[2] += b2f(y0.z) + w * b0.z;
        o[3] += b2f(y0.w) + w * b0.w;
        o[4] += b2f(y1.x) + w * b1.x;
        o[5] += b2f(y1.y) + w * b1.y;
        o[6] += b2f(y1.z) + w * b1.z;
        o[7] += b2f(y1.w) + w * b1.w;
    }
    float4 ov0 = {o[0], o[1], o[2], o[3]};
    float4 ov1 = {o[4], o[5], o[6], o[7]};
    *(float4*)(out + (size_t)t * DH + c)     = ov0;
    *(float4*)(out + (size_t)t * DH + c + 4) = ov1;
}

extern "C" void kernel_launch(void* const* d_in, const int* in_sizes, int n_in,
                              void* d_out, int out_size, void* d_ws, size_t ws_size,
                              hipStream_t stream)
{
    const float* x  = (const float*)d_in[0];
    const float* Wg = (const float*)d_in[1];
    const float* bg = (const float*)d_in[2];
    const float* W  = (const float*)d_in[3];
    const float* b  = (const float*)d_in[4];
    float* out = (float*)d_out;

    char* ws = (char*)d_ws;
    u16*   xb         = (u16*)(ws);                    // 16,777,216 B
    u16*   wbt        = (u16*)(ws + 16777216);         // 16,777,216 B
    u16*   y          = (u16*)(ws + 33554432);         // 67,108,864 B
    int*   bucket_tok = (int*)(ws + 100663296);        //    262,144 B
    float* bucket_w   = (float*)(ws + 100925440);      //    262,144 B
    int*   tk_e       = (int*)(ws + 101187584);        //    131,072 B
    float* tk_w       = (float*)(ws + 101318656);      //    131,072 B
    int*   cnt        = (int*)(ws + 101449728);        //         32 B
    float* probsum    = (float*)(ws + 101449760);      //         32 B

    hipMemsetAsync(cnt, 0, 64, stream);  // cnt + probsum (must precede router atomics)

    prep_kernel<<<2048, 512, 0, stream>>>(W, wbt, x, Wg, bg, xb,
                                          bucket_tok, bucket_w, tk_e, tk_w, cnt, probsum);
    moe_gemm_kernel<<<dim3(256), 512, 0, stream>>>(xb, wbt, bucket_tok, bucket_w, cnt, y);
    moe_gemm_tail_kernel<<<dim3(4, 4, NE), 512, 0, stream>>>(xb, wbt, bucket_tok, bucket_w, cnt, y);
    combine_kernel<<<4096, 256, 0, stream>>>(y, tk_e, tk_w, b, cnt, probsum, out, out + (size_t)T_TOK * DH);
}

// Round 13
// 246.200 us; speedup vs baseline: 1.0815x; 1.0074x over previous
//
#include <hip/hip_runtime.h>
#include <hip/hip_bf16.h>

#define T_TOK 8192
#define DH    1024
#define NE    8
#define TK    4

typedef unsigned short u16;
typedef __bf16 bf16x8 __attribute__((ext_vector_type(8)));
typedef float  f32x4  __attribute__((ext_vector_type(4)));

__device__ __forceinline__ u16 f2b(float f) {
    union { float f; unsigned u; } v; v.f = f;
    unsigned u = v.u;
    u += 0x7FFFu + ((u >> 16) & 1u);   // round-to-nearest-even
    return (u16)(u >> 16);
}
__device__ __forceinline__ float b2f(u16 h) {
    union { unsigned u; float f; } v; v.u = ((unsigned)h) << 16;
    return v.f;
}
// async global->LDS, 16B per lane; LDS dest = wave-uniform base + lane*16 (linear!)
__device__ __forceinline__ void glds16(const u16* g, u16* l) {
    __builtin_amdgcn_global_load_lds((const __attribute__((address_space(1))) void*)g,
                                     (__attribute__((address_space(3))) void*)l, 16, 0, 0);
}

#define FENCE() asm volatile("" ::: "memory")
#define SBAR()  do { FENCE(); __builtin_amdgcn_s_barrier(); FENCE(); } while (0)
// rule 18: hipcc can hoist reg-only MFMA past an inline-asm lgkmcnt; fence with sched_barrier(0)
#define WAITLGKM0() do { asm volatile("s_waitcnt lgkmcnt(0)" ::: "memory"); \
                         __builtin_amdgcn_sched_barrier(0); } while (0)
#define WAITVM(n) asm volatile("s_waitcnt vmcnt(" #n ")" ::: "memory")

// ---------------- fused prep: cast W (blocks 0..1023, 2 tiles each) + router (1024..2047) ----------------
__global__ __launch_bounds__(512) void prep_kernel(
    const float* __restrict__ W, u16* __restrict__ wbt,
    const float* __restrict__ x, const float* __restrict__ Wg, const float* __restrict__ bg,
    u16* __restrict__ xb,
    int* __restrict__ bucket_tok, float* __restrict__ bucket_w,
    int* __restrict__ tk_e, float* __restrict__ tk_w,
    int* __restrict__ cnt, float* __restrict__ probsum)
{
    __shared__ float tile2[2][64][65];   // cast path (33.3 KB)
    __shared__ int   lcnt[NE];
    __shared__ float lprob[NE];
    __shared__ int   gbase[NE];

    const int bid = blockIdx.x;
    const int tid = threadIdx.x;

    if (bid < 1024) {
        // ------- cast W -> bf16, transposed to [e][f][d]; two 64x64 tiles per block -------
        const int half = tid >> 8;            // 0..1
        const int tloc = tid & 255;
        const int r  = tloc >> 4;             // 0..15
        const int c4 = (tloc & 15) * 4;       // 0,4,...,60
        float (*tile)[65] = tile2[half];
        const int jc = bid * 2 + half;        // 0..2047
        const int f0 = (jc & 15) * 64;
        const int d0 = ((jc >> 4) & 15) * 64;
        const int e  = jc >> 8;
        const float* src = W + ((size_t)e << 20) + (size_t)d0 * DH + f0;
        #pragma unroll
        for (int i = 0; i < 4; i++) {
            const int row = i * 16 + r;
            const float4 v = *(const float4*)(src + (size_t)row * DH + c4);
            tile[row][c4]     = v.x;
            tile[row][c4 + 1] = v.y;
            tile[row][c4 + 2] = v.z;
            tile[row][c4 + 3] = v.w;
        }
        __syncthreads();
        u16* dst = wbt + ((size_t)e << 20) + (size_t)f0 * DH + d0;
        #pragma unroll
        for (int i = 0; i < 4; i++) {
            const int orow = i * 16 + r;      // f-index within tile
            ushort4 o;
            o.x = f2b(tile[c4][orow]);
            o.y = f2b(tile[c4 + 1][orow]);
            o.z = f2b(tile[c4 + 2][orow]);
            o.w = f2b(tile[c4 + 3][orow]);
            *(ushort4*)(dst + (size_t)orow * DH + c4) = o;
        }
        return;
    }

    // ------- router: logits + softmax + top4 + buckets, fused x->bf16 cast -------
    const int wv = tid >> 6, lane = tid & 63;
    const int t = (bid - 1024) * 8 + wv;
    if (tid < NE) { lcnt[tid] = 0; lprob[tid] = 0.f; }
    __syncthreads();

    float a[NE] = {};
    {
        const float* xr = x + (size_t)t * DH;
        u16* xbr = xb + (size_t)t * DH;
        const float4* wg = (const float4*)Wg;   // row d -> wg[2d] (e0..3), wg[2d+1] (e4..7)
        #pragma unroll
        for (int it = 0; it < 4; it++) {
            const int d = it * 256 + lane * 4;
            const float4 v = *(const float4*)(xr + d);
            ushort4 o;
            o.x = f2b(v.x); o.y = f2b(v.y); o.z = f2b(v.z); o.w = f2b(v.w);
            *(ushort4*)(xbr + d) = o;
            const float4 w0l = wg[2 * (d + 0)], w0h = wg[2 * (d + 0) + 1];
            const float4 w1l = wg[2 * (d + 1)], w1h = wg[2 * (d + 1) + 1];
            const float4 w2l = wg[2 * (d + 2)], w2h = wg[2 * (d + 2) + 1];
            const float4 w3l = wg[2 * (d + 3)], w3h = wg[2 * (d + 3) + 1];
            a[0] += v.x * w0l.x + v.y * w1l.x + v.z * w2l.x + v.w * w3l.x;
            a[1] += v.x * w0l.y + v.y * w1l.y + v.z * w2l.y + v.w * w3l.y;
            a[2] += v.x * w0l.z + v.y * w1l.z + v.z * w2l.z + v.w * w3l.z;
            a[3] += v.x * w0l.w + v.y * w1l.w + v.z * w2l.w + v.w * w3l.w;
            a[4] += v.x * w0h.x + v.y * w1h.x + v.z * w2h.x + v.w * w3h.x;
            a[5] += v.x * w0h.y + v.y * w1h.y + v.z * w2h.y + v.w * w3h.y;
            a[6] += v.x * w0h.z + v.y * w1h.z + v.z * w2h.z + v.w * w3h.z;
            a[7] += v.x * w0h.w + v.y * w1h.w + v.z * w2h.w + v.w * w3h.w;
        }
    }
    #pragma unroll
    for (int e = 0; e < NE; e++) {
        float v = a[e];
        #pragma unroll
        for (int off = 32; off > 0; off >>= 1) v += __shfl_down(v, off);
        a[e] = v;
    }

    int idx4[TK]; float w4[TK]; int off4[TK];
    if (lane == 0) {
        float logits[NE], probs[NE];
        float mx = -1e30f;
        #pragma unroll
        for (int e = 0; e < NE; e++) { logits[e] = a[e] + bg[e]; mx = fmaxf(mx, logits[e]); }
        float Z = 0.f;
        #pragma unroll
        for (int e = 0; e < NE; e++) { probs[e] = expf(logits[e] - mx); Z += probs[e]; }
        const float rZ = 1.f / Z;
        #pragma unroll
        for (int e = 0; e < NE; e++) probs[e] *= rZ;

        float rem2[NE];
        #pragma unroll
        for (int e = 0; e < NE; e++) rem2[e] = probs[e];
        float s4 = 0.f;
        #pragma unroll
        for (int k = 0; k < TK; k++) {   // strict > scan from 0 == jax tie-break (lowest idx)
            int best = 0; float bv = rem2[0];
            #pragma unroll
            for (int e = 1; e < NE; e++) if (rem2[e] > bv) { bv = rem2[e]; best = e; }
            idx4[k] = best; w4[k] = bv; s4 += bv; rem2[best] = -1e30f;
        }
        const float rs = 1.f / (s4 + 1e-6f);
        #pragma unroll
        for (int k = 0; k < TK; k++) {
            w4[k] *= rs;
            tk_e[t * TK + k] = idx4[k];
            tk_w[t * TK + k] = w4[k];
            off4[k] = atomicAdd(&lcnt[idx4[k]], 1);
        }
        #pragma unroll
        for (int e = 0; e < NE; e++) atomicAdd(&lprob[e], probs[e]);
    }
    __syncthreads();
    if (tid < NE) {
        gbase[tid] = atomicAdd(&cnt[tid], lcnt[tid]);
        atomicAdd(&probsum[tid], lprob[tid]);
    }
    __syncthreads();
    if (lane == 0) {
        #pragma unroll
        for (int k = 0; k < TK; k++) {
            const int e = idx4[k];
            const int slot = gbase[e] + off4[k];
            bucket_tok[e * T_TOK + slot] = (t << 2) | k;
            bucket_w[e * T_TOK + slot]   = w4[k];
        }
    }
}

// ---------------- grouped gather GEMM, 256x256 / BK=64 / 8-wave / 4-phase-per-K-tile ----------------
// R13 = R12 with ROUND-STRUCTURED home-slot bijection (one-line fix):
//  - R12's pair (2c,2c+1) made concurrent blocks span mb 0..15 -> 8MB A-panels + 2MB B
//    vs 4MB L2/XCD -> thrash (FETCH 72.5MB, per-unit 39.4us vs R9's 35.8).
//  - sigma(s) = (s>>1) + (s&1)*(own/2): block c runs tiles (c, c+own/2). Round 1 = tiles
//    0..31 (mb 0..7, 4 blocks/A-panel, 4MB working set = R9's profile); round 2 = mb 8..15.
//  - Deficit/leftover pairing unchanged; inner loop byte-identical.
__global__ __launch_bounds__(512, 2) void moe_gemm_kernel(
    const u16* __restrict__ xb, const u16* __restrict__ wbt,
    const int* __restrict__ bucket_tok, const float* __restrict__ bucket_w,
    const int* __restrict__ cnt, u16* __restrict__ y)
{
    __shared__ u16 As[2][256 * 64];   // 64 KB
    __shared__ u16 Bs[2][256 * 64];   // 64 KB
    __shared__ int   s_tok[256];
    __shared__ float s_w[256];

    const int tid  = threadIdx.x;
    const int lane = tid & 63;
    const int wid  = tid >> 6;            // 0..7
    const int wr   = wid >> 2;            // 0..1 (M)
    const int wc   = wid & 3;             // 0..3 (N)
    const int fr   = lane & 15;
    const int fq   = (lane >> 4) * 8;
    const int swz  = (fr & 7) << 3;       // u16-index XOR for frag reads
    const int gsw  = ((lane & 7) ^ (lane >> 3)) * 8;  // pre-swizzled global u16 col for staging
    const int crow = lane >> 3;           // row within 8-row chunk

    const int ALb = 2 * wid + (wid >= 4 ? 8 : 0);
    const int AHb = ALb + 8;
    const int BLb = (wid >> 1) * 8 + (wid & 1) * 2;
    const int BHb = BLb + 4;

    // expert-aligned slot map (block-uniform)
    int nt[NE];
    #pragma unroll
    for (int e = 0; e < NE; e++) nt[e] = (cnt[e] >> 8) << 2;   // full tiles per expert
    int dpfx[NE + 1], lpfx[NE + 1];
    dpfx[0] = 0; lpfx[0] = 0;
    #pragma unroll
    for (int e = 0; e < NE; e++) {
        const int own = nt[e] < 64 ? nt[e] : 64;
        dpfx[e + 1] = dpfx[e] + (64 - own);       // deficit slots, XCD-major
        lpfx[e + 1] = lpfx[e] + (nt[e] - own);    // leftover tiles, expert-major
    }
    const int xcd = blockIdx.x & 7;
    const int cc  = blockIdx.x >> 3;              // 0..31 within XCD
    const int ownx = nt[xcd] < 64 ? nt[xcd] : 64;
    const int halfx = ownx >> 1;                  // ownx is a multiple of 4

    for (int u = 0; u < 2; ++u) {
        const int s = 2 * cc + u;                 // slot within this XCD
        int e, tt;
        if (s < ownx) {                           // home tile, round-structured bijection
            e = xcd; tt = (s >> 1) + (s & 1) * halfx;
        } else {
            const int d = dpfx[xcd] + (s - ownx); // global deficit index
            if (d >= lpfx[NE]) continue;          // idle slot (uniform)
            e = 0;
            #pragma unroll
            for (int k = 1; k < NE; k++) if (lpfx[k] <= d) e = k;
            tt = 64 + (d - lpfx[e]);              // leftover tile of heavy expert
        }
        const int m0 = (tt >> 2) << 8;
        const int n0 = (tt & 3) << 8;

        __syncthreads();                   // s_tok/s_w + LDS reuse across tiles
        if (tid < 256) {
            s_tok[tid] = bucket_tok[e * T_TOK + m0 + tid];
            s_w[tid]   = bucket_w[e * T_TOK + m0 + tid];
        }
        __syncthreads();

        const int rAL0 = ALb * 8 + crow, rAL1 = rAL0 + 8;
        const int rAH0 = AHb * 8 + crow, rAH1 = rAH0 + 8;
        const int tAL0 = s_tok[rAL0], tAL1 = s_tok[rAL1];
        const int tAH0 = s_tok[rAH0], tAH1 = s_tok[rAH1];
        const u16* gAL0 = xb + (size_t)(tAL0 >> 2) * DH + gsw;
        const u16* gAL1 = xb + (size_t)(tAL1 >> 2) * DH + gsw;
        const u16* gAH0 = xb + (size_t)(tAH0 >> 2) * DH + gsw;
        const u16* gAH1 = xb + (size_t)(tAH1 >> 2) * DH + gsw;
        const u16* wbe  = wbt + ((size_t)e << 20);
        const u16* gBL0 = wbe + (size_t)(n0 + BLb * 8 + crow) * DH + gsw;
        const u16* gBL1 = gBL0 + (size_t)8 * DH;
        const u16* gBH0 = wbe + (size_t)(n0 + BHb * 8 + crow) * DH + gsw;
        const u16* gBH1 = gBH0 + (size_t)8 * DH;

        f32x4 acc[8][4] = {};

        #pragma unroll
        for (int kt = 0; kt < 2; kt++) {
            const int ko = kt * 64; const int p = kt;
            glds16(gAL0 + ko, &As[p][ALb * 512]); glds16(gAL1 + ko, &As[p][(ALb + 1) * 512]);
            glds16(gAH0 + ko, &As[p][AHb * 512]); glds16(gAH1 + ko, &As[p][(AHb + 1) * 512]);
            glds16(gBL0 + ko, &Bs[p][BLb * 512]); glds16(gBL1 + ko, &Bs[p][(BLb + 1) * 512]);
            glds16(gBH0 + ko, &Bs[p][BHb * 512]); glds16(gBH1 + ko, &Bs[p][(BHb + 1) * 512]);
        }
        WAITVM(8);            // tile 0 resident (tile 1 in flight)
        SBAR();

        const int arow = (wr * 128 + fr) * 64;    // u16 base of this lane's A frag rows
        const int brow = (wc * 64  + fr) * 64;
        const int c0 = fq ^ swz;                  // k-half 0 column (u16)
        const int c1 = (32 + fq) ^ swz;           // k-half 1 column

        bf16x8 afL[4][2], afH[4][2], bfL[2][2], bfH[2][2];

        for (int kt = 0; kt < 16; ++kt) {
            const int p = kt & 1;
            const u16* Ap = &As[p][0];
            const u16* Bp = &Bs[p][0];

            // ---- P1: read afL(8)+bfL(4); stage A-H of kt+1 -> buf p^1; MFMA miL x njL ----
            #pragma unroll
            for (int mi = 0; mi < 4; mi++) {
                afL[mi][0] = *(const bf16x8*)&Ap[arow + mi * 1024 + c0];
                afL[mi][1] = *(const bf16x8*)&Ap[arow + mi * 1024 + c1];
            }
            #pragma unroll
            for (int nj = 0; nj < 2; nj++) {
                bfL[nj][0] = *(const bf16x8*)&Bp[brow + nj * 1024 + c0];
                bfL[nj][1] = *(const bf16x8*)&Bp[brow + nj * 1024 + c1];
            }
            if (kt >= 1 && kt <= 14) {             // A-H rows of p^1 died at end-P3 of kt-1
                const int ko = (kt + 1) * 64; const int q = (kt + 1) & 1;
                glds16(gAH0 + ko, &As[q][AHb * 512]);
                glds16(gAH1 + ko, &As[q][(AHb + 1) * 512]);
            }
            asm volatile("s_waitcnt lgkmcnt(8)" ::: "memory");   // 12-read phase hint (template)
            SBAR(); WAITLGKM0();
            __builtin_amdgcn_s_setprio(1);
            #pragma unroll
            for (int mi = 0; mi < 4; mi++)
                #pragma unroll
                for (int nj = 0; nj < 2; nj++) {
                    acc[mi][nj] = __builtin_amdgcn_mfma_f32_16x16x32_bf16(afL[mi][0], bfL[nj][0], acc[mi][nj], 0, 0, 0);
                    acc[mi][nj] = __builtin_amdgcn_mfma_f32_16x16x32_bf16(afL[mi][1], bfL[nj][1], acc[mi][nj], 0, 0, 0);
                }
            __builtin_amdgcn_s_setprio(0);
            SBAR();                                // A-L/B-L rows of buf p now dead

            // ---- P2: read bfH(4); stage A-L of kt+2 -> buf p; MFMA miL x njH ----
            #pragma unroll
            for (int nj = 0; nj < 2; nj++) {
                bfH[nj][0] = *(const bf16x8*)&Bp[brow + (nj + 2) * 1024 + c0];
                bfH[nj][1] = *(const bf16x8*)&Bp[brow + (nj + 2) * 1024 + c1];
            }
            if (kt <= 13) {
                const int ko = (kt + 2) * 64;
                glds16(gAL0 + ko, &As[p][ALb * 512]);
                glds16(gAL1 + ko, &As[p][(ALb + 1) * 512]);
            }
            SBAR(); WAITLGKM0();
            __builtin_amdgcn_s_setprio(1);
            #pragma unroll
            for (int mi = 0; mi < 4; mi++)
                #pragma unroll
                for (int nj = 0; nj < 2; nj++) {
                    acc[mi][nj + 2] = __builtin_amdgcn_mfma_f32_16x16x32_bf16(afL[mi][0], bfH[nj][0], acc[mi][nj + 2], 0, 0, 0);
                    acc[mi][nj + 2] = __builtin_amdgcn_mfma_f32_16x16x32_bf16(afL[mi][1], bfH[nj][1], acc[mi][nj + 2], 0, 0, 0);
                }
            __builtin_amdgcn_s_setprio(0);
            SBAR();                                // B-H rows of buf p now dead

            // ---- P3: read afH(8); stage B-L of kt+2 -> buf p; MFMA miH x njH ----
            #pragma unroll
            for (int mi = 0; mi < 4; mi++) {
                afH[mi][0] = *(const bf16x8*)&Ap[arow + (mi + 4) * 1024 + c0];
                afH[mi][1] = *(const bf16x8*)&Ap[arow + (mi + 4) * 1024 + c1];
            }
            if (kt <= 13) {
                const int ko = (kt + 2) * 64;
                glds16(gBL0 + ko, &Bs[p][BLb * 512]);
                glds16(gBL1 + ko, &Bs[p][(BLb + 1) * 512]);
            }
            SBAR(); WAITLGKM0();
            __builtin_amdgcn_s_setprio(1);
            #pragma unroll
            for (int mi = 0; mi < 4; mi++)
                #pragma unroll
                for (int nj = 0; nj < 2; nj++) {
                    acc[mi + 4][nj + 2] = __builtin_amdgcn_mfma_f32_16x16x32_bf16(afH[mi][0], bfH[nj][0], acc[mi + 4][nj + 2], 0, 0, 0);
                    acc[mi + 4][nj + 2] = __builtin_amdgcn_mfma_f32_16x16x32_bf16(afH[mi][1], bfH[nj][1], acc[mi + 4][nj + 2], 0, 0, 0);
                }
            __builtin_amdgcn_s_setprio(0);
            SBAR();                                // A-H rows of buf p now dead

            // ---- P4: stage B-H of kt+2 -> buf p; MFMA miH x njL (regs only); counted vmcnt ----
            if (kt <= 13) {
                const int ko = (kt + 2) * 64;
                glds16(gBH0 + ko, &Bs[p][BHb * 512]);
                glds16(gBH1 + ko, &Bs[p][(BHb + 1) * 512]);
            }
            __builtin_amdgcn_s_setprio(1);
            #pragma unroll
            for (int mi = 0; mi < 4; mi++)
                #pragma unroll
                for (int nj = 0; nj < 2; nj++) {
                    acc[mi + 4][nj] = __builtin_amdgcn_mfma_f32_16x16x32_bf16(afH[mi][0], bfL[nj][0], acc[mi + 4][nj], 0, 0, 0);
                    acc[mi + 4][nj] = __builtin_amdgcn_mfma_f32_16x16x32_bf16(afH[mi][1], bfL[nj][1], acc[mi + 4][nj], 0, 0, 0);
                }
            __builtin_amdgcn_s_setprio(0);
            // newer-than-(kt+1) loads = kt+2's A-L,B-L,B-H = 6 -> vmcnt(6) => tile kt+1 resident
            if (kt <= 13)      WAITVM(6);
            else if (kt == 14) WAITVM(0);          // drain for tile 15
            SBAR();
        }

        // C/D layout: col = lane&15, row = (lane>>4)*4 + r
        const int cl = lane & 15;
        const int rb = (lane >> 4) * 4;
        #pragma unroll
        for (int mi = 0; mi < 8; mi++) {
            #pragma unroll
            for (int r = 0; r < 4; r++) {
                const int srow = wr * 128 + mi * 16 + rb + r;
                const int tok = s_tok[srow];
                const float w = s_w[srow];
                u16* yr = y + (size_t)tok * DH + (n0 + wc * 64 + cl);
                #pragma unroll
                for (int nj = 0; nj < 4; nj++)
                    yr[nj * 16] = f2b(acc[mi][nj][r] * w);
            }
        }
    }
}

// ---------------- tail GEMM: remainder rows [floor(M/256)*256, M) per expert ----------------
__global__ __launch_bounds__(512) void moe_gemm_tail_kernel(
    const u16* __restrict__ xb, const u16* __restrict__ wbt,
    const int* __restrict__ bucket_tok, const float* __restrict__ bucket_w,
    const int* __restrict__ cnt, u16* __restrict__ y)
{
    __shared__ u16 As[2][64 * 64];    // 16 KB
    __shared__ u16 Bs[2][256 * 64];   // 64 KB
    __shared__ int   s_tok[64];
    __shared__ float s_w[64];

    const int e  = blockIdx.z;
    const int sb = blockIdx.y;         // 0..3: 64-row sub-tile of the remainder
    const int nb = blockIdx.x;         // 0..3: 256-col block
    const int M  = cnt[e];
    const int m0 = ((M >> 8) << 8) + sb * 64;
    if (m0 >= M) return;
    const int n0 = nb << 8;

    const int tid  = threadIdx.x;
    const int lane = tid & 63;
    const int w8   = tid >> 6;         // 0..7: col group (32 cols each)
    const int fr   = lane & 15;
    const int fq   = (lane >> 4) * 8;
    const int swz  = (fr & 7) << 3;
    const int gsw  = ((lane & 7) ^ (lane >> 3)) * 8;
    const int crow = lane >> 3;

    if (tid < 64) {
        const int slot = m0 + tid;
        if (slot < M) { s_tok[tid] = bucket_tok[e * T_TOK + slot]; s_w[tid] = bucket_w[e * T_TOK + slot]; }
        else          { s_tok[tid] = -1;                           s_w[tid] = 0.f; }
    }
    __syncthreads();

    const int tA = s_tok[w8 * 8 + crow];
    const u16* gA = xb + (size_t)(tA >= 0 ? (tA >> 2) : 0) * DH + gsw;
    const u16* wbe = wbt + ((size_t)e << 20);
    const u16* gB0 = wbe + (size_t)(n0 + (4 * w8 + 0) * 8 + crow) * DH + gsw;
    const u16* gB1 = wbe + (size_t)(n0 + (4 * w8 + 1) * 8 + crow) * DH + gsw;
    const u16* gB2 = wbe + (size_t)(n0 + (4 * w8 + 2) * 8 + crow) * DH + gsw;
    const u16* gB3 = wbe + (size_t)(n0 + (4 * w8 + 3) * 8 + crow) * DH + gsw;

    f32x4 acc[4][2] = {};

    #define TSTAGE(kt) do { const int p_ = (kt) & 1; const int ko_ = (kt) * 64;         \
        glds16(gA  + ko_, &As[p_][w8 * 512]);                                           \
        glds16(gB0 + ko_, &Bs[p_][(4 * w8 + 0) * 512]);                                 \
        glds16(gB1 + ko_, &Bs[p_][(4 * w8 + 1) * 512]);                                 \
        glds16(gB2 + ko_, &Bs[p_][(4 * w8 + 2) * 512]);                                 \
        glds16(gB3 + ko_, &Bs[p_][(4 * w8 + 3) * 512]); } while (0)

    TSTAGE(0); TSTAGE(1);              // 10 in flight per wave
    WAITVM(5);                         // tile 0 resident
    SBAR();

    const int c0 = fq ^ swz;
    const int c1 = (32 + fq) ^ swz;

    for (int kt = 0; kt < 16; ++kt) {
        const int p = kt & 1;
        bf16x8 af[4][2], bf[2][2];
        #pragma unroll
        for (int mi = 0; mi < 4; mi++) {
            af[mi][0] = *(const bf16x8*)&As[p][(mi * 16 + fr) * 64 + c0];
            af[mi][1] = *(const bf16x8*)&As[p][(mi * 16 + fr) * 64 + c1];
        }
        #pragma unroll
        for (int nj = 0; nj < 2; nj++) {
            bf[nj][0] = *(const bf16x8*)&Bs[p][(w8 * 32 + nj * 16 + fr) * 64 + c0];
            bf[nj][1] = *(const bf16x8*)&Bs[p][(w8 * 32 + nj * 16 + fr) * 64 + c1];
        }
        WAITLGKM0();
        __builtin_amdgcn_s_setprio(1);
        #pragma unroll
        for (int mi = 0; mi < 4; mi++)
            #pragma unroll
            for (int nj = 0; nj < 2; nj++) {
                acc[mi][nj] = __builtin_amdgcn_mfma_f32_16x16x32_bf16(af[mi][0], bf[nj][0], acc[mi][nj], 0, 0, 0);
                acc[mi][nj] = __builtin_amdgcn_mfma_f32_16x16x32_bf16(af[mi][1], bf[nj][1], acc[mi][nj], 0, 0, 0);
            }
        __builtin_amdgcn_s_setprio(0);
        SBAR();                        // all waves done reading buf p
        if (kt + 2 < 16) { TSTAGE(kt + 2); WAITVM(5); }   // tile kt+1 resident
        else if (kt == 14) WAITVM(0);                     // drain for tile 15
        if (kt < 15) SBAR();
    }
    #undef TSTAGE

    // C/D layout: col = lane&15, row = (lane>>4)*4 + r
    const int cl = lane & 15;
    const int rb = (lane >> 4) * 4;
    #pragma unroll
    for (int mi = 0; mi < 4; mi++) {
        #pragma unroll
        for (int r = 0; r < 4; r++) {
            const int srow = mi * 16 + rb + r;
            const int tok = s_tok[srow];
            if (tok < 0) continue;
            const float w = s_w[srow];
            u16* yr = y + (size_t)tok * DH + (n0 + w8 * 32 + cl);
            #pragma unroll
            for (int nj = 0; nj < 2; nj++)
                yr[nj * 16] = f2b(acc[mi][nj][r] * w);
        }
    }
}

// ---------------- combine: out[t] = sum_k y[t*4+k] + sum_k w_k*b[e_k]; block 0 does aux ----------------
__global__ __launch_bounds__(256) void combine_kernel(
    const u16* __restrict__ y, const int* __restrict__ tk_e, const float* __restrict__ tk_w,
    const float* __restrict__ bexp,
    const int* __restrict__ cnt, const float* __restrict__ probsum,
    float* __restrict__ out, float* __restrict__ out_aux)
{
    if (blockIdx.x == 0 && threadIdx.x == 0) {
        float s = 0.f;
        for (int e = 0; e < NE; e++) s += (float)cnt[e] * probsum[e];
        out_aux[0] = s * (float)NE / ((float)T_TOK * (float)T_TOK);
    }
    const int t = blockIdx.x * 2 + (threadIdx.x >> 7);
    const int c = (threadIdx.x & 127) * 8;
    float o[8] = {};
    #pragma unroll
    for (int k = 0; k < TK; k++) {
        const int e   = tk_e[t * TK + k];
        const float w = tk_w[t * TK + k];
        const u16* yp = y + ((size_t)(t * TK + k)) * DH + c;
        const ushort4 y0 = *(const ushort4*)(yp);
        const ushort4 y1 = *(const ushort4*)(yp + 4);
        const float4  b0 = *(const float4*)(bexp + (size_t)e * DH + c);
        const float4  b1 = *(const float4*)(bexp + (size_t)e * DH + c + 4);
        o[0] += b2f(y0.x) + w * b0.x;
        o[1] += b2f(y0.y) + w * b0.y;
        o[2] += b2f(y0.z) + w * b0.z;
        o[3] += b2f(y0.w) + w * b0.w;
        o[4] += b2f(y1.x) + w * b1.x;
        o[5] += b2f(y1.y) + w * b1.y;
        o[6] += b2f(y1.z) + w * b1.z;
        o[7] += b2f(y1.w) + w * b1.w;
    }
    float4 ov0 = {o[0], o[1], o[2], o[3]};
    float4 ov1 = {o[4], o[5], o[6], o[7]};
    *(float4*)(out + (size_t)t * DH + c)     = ov0;
    *(float4*)(out + (size_t)t * DH + c + 4) = ov1;
}

extern "C" void kernel_launch(void* const* d_in, const int* in_sizes, int n_in,
                              void* d_out, int out_size, void* d_ws, size_t ws_size,
                              hipStream_t stream)
{
    const float* x  = (const float*)d_in[0];
    const float* Wg = (const float*)d_in[1];
    const float* bg = (const float*)d_in[2];
    const float* W  = (const float*)d_in[3];
    const float* b  = (const float*)d_in[4];
    float* out = (float*)d_out;

    char* ws = (char*)d_ws;
    u16*   xb         = (u16*)(ws);                    // 16,777,216 B
    u16*   wbt        = (u16*)(ws + 16777216);         // 16,777,216 B
    u16*   y          = (u16*)(ws + 33554432);         // 67,108,864 B
    int*   bucket_tok = (int*)(ws + 100663296);        //    262,144 B
    float* bucket_w   = (float*)(ws + 100925440);      //    262,144 B
    int*   tk_e       = (int*)(ws + 101187584);        //    131,072 B
    float* tk_w       = (float*)(ws + 101318656);      //    131,072 B
    int*   cnt        = (int*)(ws + 101449728);        //         32 B
    float* probsum    = (float*)(ws + 101449760);      //         32 B

    hipMemsetAsync(cnt, 0, 64, stream);  // cnt + probsum (must precede router atomics)

    prep_kernel<<<2048, 512, 0, stream>>>(W, wbt, x, Wg, bg, xb,
                                          bucket_tok, bucket_w, tk_e, tk_w, cnt, probsum);
    moe_gemm_kernel<<<dim3(256), 512, 0, stream>>>(xb, wbt, bucket_tok, bucket_w, cnt, y);
    moe_gemm_tail_kernel<<<dim3(4, 4, NE), 512, 0, stream>>>(xb, wbt, bucket_tok, bucket_w, cnt, y);
    combine_kernel<<<4096, 256, 0, stream>>>(y, tk_e, tk_w, b, cnt, probsum, out, out + (size_t)T_TOK * DH);
}

// Round 14
// 240.372 us; speedup vs baseline: 1.1077x; 1.0242x over previous
//
#include <hip/hip_runtime.h>
#include <hip/hip_bf16.h>

#define T_TOK 8192
#define DH    1024
#define NE    8
#define TK    4

typedef unsigned short u16;
typedef __bf16 bf16x8 __attribute__((ext_vector_type(8)));
typedef float  f32x4  __attribute__((ext_vector_type(4)));

__device__ __forceinline__ u16 f2b(float f) {
    union { float f; unsigned u; } v; v.f = f;
    unsigned u = v.u;
    u += 0x7FFFu + ((u >> 16) & 1u);   // round-to-nearest-even
    return (u16)(u >> 16);
}
__device__ __forceinline__ float b2f(u16 h) {
    union { unsigned u; float f; } v; v.u = ((unsigned)h) << 16;
    return v.f;
}
// async global->LDS, 16B per lane; LDS dest = wave-uniform base + lane*16 (linear!)
__device__ __forceinline__ void glds16(const u16* g, u16* l) {
    __builtin_amdgcn_global_load_lds((const __attribute__((address_space(1))) void*)g,
                                     (__attribute__((address_space(3))) void*)l, 16, 0, 0);
}

#define FENCE() asm volatile("" ::: "memory")
#define SBAR()  do { FENCE(); __builtin_amdgcn_s_barrier(); FENCE(); } while (0)
// rule 18: hipcc can hoist reg-only MFMA past an inline-asm lgkmcnt; fence with sched_barrier(0)
#define WAITLGKM0() do { asm volatile("s_waitcnt lgkmcnt(0)" ::: "memory"); \
                         __builtin_amdgcn_sched_barrier(0); } while (0)
#define WAITVM(n) asm volatile("s_waitcnt vmcnt(" #n ")" ::: "memory")

// ---------------- fused prep: cast W (blocks 0..1023, 2 tiles each) + router (1024..2047) ----------------
__global__ __launch_bounds__(512) void prep_kernel(
    const float* __restrict__ W, u16* __restrict__ wbt,
    const float* __restrict__ x, const float* __restrict__ Wg, const float* __restrict__ bg,
    u16* __restrict__ xb,
    int* __restrict__ bucket_tok, float* __restrict__ bucket_w,
    int* __restrict__ tk_e, float* __restrict__ tk_w,
    int* __restrict__ cnt, float* __restrict__ probsum)
{
    __shared__ float tile2[2][64][65];   // cast path (33.3 KB)
    __shared__ int   lcnt[NE];
    __shared__ float lprob[NE];
    __shared__ int   gbase[NE];

    const int bid = blockIdx.x;
    const int tid = threadIdx.x;

    if (bid < 1024) {
        // ------- cast W -> bf16, transposed to [e][f][d]; two 64x64 tiles per block -------
        const int half = tid >> 8;            // 0..1
        const int tloc = tid & 255;
        const int r  = tloc >> 4;             // 0..15
        const int c4 = (tloc & 15) * 4;       // 0,4,...,60
        float (*tile)[65] = tile2[half];
        const int jc = bid * 2 + half;        // 0..2047
        const int f0 = (jc & 15) * 64;
        const int d0 = ((jc >> 4) & 15) * 64;
        const int e  = jc >> 8;
        const float* src = W + ((size_t)e << 20) + (size_t)d0 * DH + f0;
        #pragma unroll
        for (int i = 0; i < 4; i++) {
            const int row = i * 16 + r;
            const float4 v = *(const float4*)(src + (size_t)row * DH + c4);
            tile[row][c4]     = v.x;
            tile[row][c4 + 1] = v.y;
            tile[row][c4 + 2] = v.z;
            tile[row][c4 + 3] = v.w;
        }
        __syncthreads();
        u16* dst = wbt + ((size_t)e << 20) + (size_t)f0 * DH + d0;
        #pragma unroll
        for (int i = 0; i < 4; i++) {
            const int orow = i * 16 + r;      // f-index within tile
            ushort4 o;
            o.x = f2b(tile[c4][orow]);
            o.y = f2b(tile[c4 + 1][orow]);
            o.z = f2b(tile[c4 + 2][orow]);
            o.w = f2b(tile[c4 + 3][orow]);
            *(ushort4*)(dst + (size_t)orow * DH + c4) = o;
        }
        return;
    }

    // ------- router: logits + softmax + top4 + buckets, fused x->bf16 cast -------
    const int wv = tid >> 6, lane = tid & 63;
    const int t = (bid - 1024) * 8 + wv;
    if (tid < NE) { lcnt[tid] = 0; lprob[tid] = 0.f; }
    __syncthreads();

    float a[NE] = {};
    {
        const float* xr = x + (size_t)t * DH;
        u16* xbr = xb + (size_t)t * DH;
        const float4* wg = (const float4*)Wg;   // row d -> wg[2d] (e0..3), wg[2d+1] (e4..7)
        #pragma unroll
        for (int it = 0; it < 4; it++) {
            const int d = it * 256 + lane * 4;
            const float4 v = *(const float4*)(xr + d);
            ushort4 o;
            o.x = f2b(v.x); o.y = f2b(v.y); o.z = f2b(v.z); o.w = f2b(v.w);
            *(ushort4*)(xbr + d) = o;
            const float4 w0l = wg[2 * (d + 0)], w0h = wg[2 * (d + 0) + 1];
            const float4 w1l = wg[2 * (d + 1)], w1h = wg[2 * (d + 1) + 1];
            const float4 w2l = wg[2 * (d + 2)], w2h = wg[2 * (d + 2) + 1];
            const float4 w3l = wg[2 * (d + 3)], w3h = wg[2 * (d + 3) + 1];
            a[0] += v.x * w0l.x + v.y * w1l.x + v.z * w2l.x + v.w * w3l.x;
            a[1] += v.x * w0l.y + v.y * w1l.y + v.z * w2l.y + v.w * w3l.y;
            a[2] += v.x * w0l.z + v.y * w1l.z + v.z * w2l.z + v.w * w3l.z;
            a[3] += v.x * w0l.w + v.y * w1l.w + v.z * w2l.w + v.w * w3l.w;
            a[4] += v.x * w0h.x + v.y * w1h.x + v.z * w2h.x + v.w * w3h.x;
            a[5] += v.x * w0h.y + v.y * w1h.y + v.z * w2h.y + v.w * w3h.y;
            a[6] += v.x * w0h.z + v.y * w1h.z + v.z * w2h.z + v.w * w3h.z;
            a[7] += v.x * w0h.w + v.y * w1h.w + v.z * w2h.w + v.w * w3h.w;
        }
    }
    #pragma unroll
    for (int e = 0; e < NE; e++) {
        float v = a[e];
        #pragma unroll
        for (int off = 32; off > 0; off >>= 1) v += __shfl_down(v, off);
        a[e] = v;
    }

    int idx4[TK]; float w4[TK]; int off4[TK];
    if (lane == 0) {
        float logits[NE], probs[NE];
        float mx = -1e30f;
        #pragma unroll
        for (int e = 0; e < NE; e++) { logits[e] = a[e] + bg[e]; mx = fmaxf(mx, logits[e]); }
        float Z = 0.f;
        #pragma unroll
        for (int e = 0; e < NE; e++) { probs[e] = expf(logits[e] - mx); Z += probs[e]; }
        const float rZ = 1.f / Z;
        #pragma unroll
        for (int e = 0; e < NE; e++) probs[e] *= rZ;

        float rem2[NE];
        #pragma unroll
        for (int e = 0; e < NE; e++) rem2[e] = probs[e];
        float s4 = 0.f;
        #pragma unroll
        for (int k = 0; k < TK; k++) {   // strict > scan from 0 == jax tie-break (lowest idx)
            int best = 0; float bv = rem2[0];
            #pragma unroll
            for (int e = 1; e < NE; e++) if (rem2[e] > bv) { bv = rem2[e]; best = e; }
            idx4[k] = best; w4[k] = bv; s4 += bv; rem2[best] = -1e30f;
        }
        const float rs = 1.f / (s4 + 1e-6f);
        #pragma unroll
        for (int k = 0; k < TK; k++) {
            w4[k] *= rs;
            tk_e[t * TK + k] = idx4[k];
            tk_w[t * TK + k] = w4[k];
            off4[k] = atomicAdd(&lcnt[idx4[k]], 1);
        }
        #pragma unroll
        for (int e = 0; e < NE; e++) atomicAdd(&lprob[e], probs[e]);
    }
    __syncthreads();
    if (tid < NE) {
        gbase[tid] = atomicAdd(&cnt[tid], lcnt[tid]);
        atomicAdd(&probsum[tid], lprob[tid]);
    }
    __syncthreads();
    if (lane == 0) {
        #pragma unroll
        for (int k = 0; k < TK; k++) {
            const int e = idx4[k];
            const int slot = gbase[e] + off4[k];
            bucket_tok[e * T_TOK + slot] = (t << 2) | k;
            bucket_w[e * T_TOK + slot]   = w4[k];
        }
    }
}

// ---------------- grouped gather GEMM + fused tail, one dispatch ----------------
// R14 = R13 main path VERBATIM (839 TF ~= m248's 848 TF grouped-GEMM reference; FETCH 49MB;
// declared done). Tail kernel merged as blocks 256..383 via a BLOCK-LEVEL branch (prep_kernel
// pattern, not R7's in-loop anti-pattern): deletes one ~8us launch gap and lets tail blocks
// backfill CUs freed by early-exiting idle-slot main blocks. Tail aliases main LDS (80KB of
// the 130KB footprint). Main K-loop untouched.
__global__ __launch_bounds__(512, 2) void moe_gemm_kernel(
    const u16* __restrict__ xb, const u16* __restrict__ wbt,
    const int* __restrict__ bucket_tok, const float* __restrict__ bucket_w,
    const int* __restrict__ cnt, u16* __restrict__ y)
{
    __shared__ u16 As[2][256 * 64];   // 64 KB
    __shared__ u16 Bs[2][256 * 64];   // 64 KB
    __shared__ int   s_tok[256];
    __shared__ float s_w[256];

    const int tid  = threadIdx.x;
    const int lane = tid & 63;
    const int wid  = tid >> 6;            // 0..7

    if (blockIdx.x >= 256) {
        // ================= tail path: remainder rows [floor(M/256)*256, M) =================
        const int k0 = blockIdx.x - 256;   // 0..127
        const int e  = k0 >> 4;
        const int sb = (k0 >> 2) & 3;
        const int nb = k0 & 3;
        const int M  = cnt[e];
        const int m0 = ((M >> 8) << 8) + sb * 64;
        if (m0 >= M) return;
        const int n0 = nb << 8;

        u16* AsF = &As[0][0];              // tail uses [2][64*64]  = 16 KB
        u16* BsF = &Bs[0][0];              // tail uses [2][256*64] = 64 KB

        const int w8   = wid;              // 0..7: col group (32 cols each)
        const int fr   = lane & 15;
        const int fq   = (lane >> 4) * 8;
        const int swz  = (fr & 7) << 3;
        const int gsw  = ((lane & 7) ^ (lane >> 3)) * 8;
        const int crow = lane >> 3;

        if (tid < 64) {
            const int slot = m0 + tid;
            if (slot < M) { s_tok[tid] = bucket_tok[e * T_TOK + slot]; s_w[tid] = bucket_w[e * T_TOK + slot]; }
            else          { s_tok[tid] = -1;                           s_w[tid] = 0.f; }
        }
        __syncthreads();

        const int tA = s_tok[w8 * 8 + crow];
        const u16* gA = xb + (size_t)(tA >= 0 ? (tA >> 2) : 0) * DH + gsw;
        const u16* wbe = wbt + ((size_t)e << 20);
        const u16* gB0 = wbe + (size_t)(n0 + (4 * w8 + 0) * 8 + crow) * DH + gsw;
        const u16* gB1 = wbe + (size_t)(n0 + (4 * w8 + 1) * 8 + crow) * DH + gsw;
        const u16* gB2 = wbe + (size_t)(n0 + (4 * w8 + 2) * 8 + crow) * DH + gsw;
        const u16* gB3 = wbe + (size_t)(n0 + (4 * w8 + 3) * 8 + crow) * DH + gsw;

        f32x4 acc[4][2] = {};

        #define TSTAGE(kt) do { const int p_ = (kt) & 1; const int ko_ = (kt) * 64;         \
            glds16(gA  + ko_, &AsF[p_ * 4096  + w8 * 512]);                                 \
            glds16(gB0 + ko_, &BsF[p_ * 16384 + (4 * w8 + 0) * 512]);                       \
            glds16(gB1 + ko_, &BsF[p_ * 16384 + (4 * w8 + 1) * 512]);                       \
            glds16(gB2 + ko_, &BsF[p_ * 16384 + (4 * w8 + 2) * 512]);                       \
            glds16(gB3 + ko_, &BsF[p_ * 16384 + (4 * w8 + 3) * 512]); } while (0)

        TSTAGE(0); TSTAGE(1);              // 10 in flight per wave
        WAITVM(5);                         // tile 0 resident
        SBAR();

        const int c0 = fq ^ swz;
        const int c1 = (32 + fq) ^ swz;

        for (int kt = 0; kt < 16; ++kt) {
            const int p = kt & 1;
            bf16x8 af[4][2], bf[2][2];
            #pragma unroll
            for (int mi = 0; mi < 4; mi++) {
                af[mi][0] = *(const bf16x8*)&AsF[p * 4096 + (mi * 16 + fr) * 64 + c0];
                af[mi][1] = *(const bf16x8*)&AsF[p * 4096 + (mi * 16 + fr) * 64 + c1];
            }
            #pragma unroll
            for (int nj = 0; nj < 2; nj++) {
                bf[nj][0] = *(const bf16x8*)&BsF[p * 16384 + (w8 * 32 + nj * 16 + fr) * 64 + c0];
                bf[nj][1] = *(const bf16x8*)&BsF[p * 16384 + (w8 * 32 + nj * 16 + fr) * 64 + c1];
            }
            WAITLGKM0();
            __builtin_amdgcn_s_setprio(1);
            #pragma unroll
            for (int mi = 0; mi < 4; mi++)
                #pragma unroll
                for (int nj = 0; nj < 2; nj++) {
                    acc[mi][nj] = __builtin_amdgcn_mfma_f32_16x16x32_bf16(af[mi][0], bf[nj][0], acc[mi][nj], 0, 0, 0);
                    acc[mi][nj] = __builtin_amdgcn_mfma_f32_16x16x32_bf16(af[mi][1], bf[nj][1], acc[mi][nj], 0, 0, 0);
                }
            __builtin_amdgcn_s_setprio(0);
            SBAR();                        // all waves done reading buf p
            if (kt + 2 < 16) { TSTAGE(kt + 2); WAITVM(5); }   // tile kt+1 resident
            else if (kt == 14) WAITVM(0);                     // drain for tile 15
            if (kt < 15) SBAR();
        }
        #undef TSTAGE

        // C/D layout: col = lane&15, row = (lane>>4)*4 + r
        const int cl = lane & 15;
        const int rb = (lane >> 4) * 4;
        #pragma unroll
        for (int mi = 0; mi < 4; mi++) {
            #pragma unroll
            for (int r = 0; r < 4; r++) {
                const int srow = mi * 16 + rb + r;
                const int tok = s_tok[srow];
                if (tok < 0) continue;
                const float w = s_w[srow];
                u16* yr = y + (size_t)tok * DH + (n0 + w8 * 32 + cl);
                #pragma unroll
                for (int nj = 0; nj < 2; nj++)
                    yr[nj * 16] = f2b(acc[mi][nj][r] * w);
            }
        }
        return;
    }

    // ================= main path: R13 verbatim =================
    const int wr   = wid >> 2;            // 0..1 (M)
    const int wc   = wid & 3;             // 0..3 (N)
    const int fr   = lane & 15;
    const int fq   = (lane >> 4) * 8;
    const int swz  = (fr & 7) << 3;       // u16-index XOR for frag reads
    const int gsw  = ((lane & 7) ^ (lane >> 3)) * 8;  // pre-swizzled global u16 col for staging
    const int crow = lane >> 3;           // row within 8-row chunk

    const int ALb = 2 * wid + (wid >= 4 ? 8 : 0);
    const int AHb = ALb + 8;
    const int BLb = (wid >> 1) * 8 + (wid & 1) * 2;
    const int BHb = BLb + 4;

    // expert-aligned slot map (block-uniform)
    int nt[NE];
    #pragma unroll
    for (int e = 0; e < NE; e++) nt[e] = (cnt[e] >> 8) << 2;   // full tiles per expert
    int dpfx[NE + 1], lpfx[NE + 1];
    dpfx[0] = 0; lpfx[0] = 0;
    #pragma unroll
    for (int e = 0; e < NE; e++) {
        const int own = nt[e] < 64 ? nt[e] : 64;
        dpfx[e + 1] = dpfx[e] + (64 - own);       // deficit slots, XCD-major
        lpfx[e + 1] = lpfx[e] + (nt[e] - own);    // leftover tiles, expert-major
    }
    const int xcd = blockIdx.x & 7;
    const int cc  = blockIdx.x >> 3;              // 0..31 within XCD
    const int ownx = nt[xcd] < 64 ? nt[xcd] : 64;
    const int halfx = ownx >> 1;                  // ownx is a multiple of 4

    for (int u = 0; u < 2; ++u) {
        const int s = 2 * cc + u;                 // slot within this XCD
        int e, tt;
        if (s < ownx) {                           // home tile, round-structured bijection
            e = xcd; tt = (s >> 1) + (s & 1) * halfx;
        } else {
            const int d = dpfx[xcd] + (s - ownx); // global deficit index
            if (d >= lpfx[NE]) continue;          // idle slot (uniform)
            e = 0;
            #pragma unroll
            for (int k = 1; k < NE; k++) if (lpfx[k] <= d) e = k;
            tt = 64 + (d - lpfx[e]);              // leftover tile of heavy expert
        }
        const int m0 = (tt >> 2) << 8;
        const int n0 = (tt & 3) << 8;

        __syncthreads();                   // s_tok/s_w + LDS reuse across tiles
        if (tid < 256) {
            s_tok[tid] = bucket_tok[e * T_TOK + m0 + tid];
            s_w[tid]   = bucket_w[e * T_TOK + m0 + tid];
        }
        __syncthreads();

        const int rAL0 = ALb * 8 + crow, rAL1 = rAL0 + 8;
        const int rAH0 = AHb * 8 + crow, rAH1 = rAH0 + 8;
        const int tAL0 = s_tok[rAL0], tAL1 = s_tok[rAL1];
        const int tAH0 = s_tok[rAH0], tAH1 = s_tok[rAH1];
        const u16* gAL0 = xb + (size_t)(tAL0 >> 2) * DH + gsw;
        const u16* gAL1 = xb + (size_t)(tAL1 >> 2) * DH + gsw;
        const u16* gAH0 = xb + (size_t)(tAH0 >> 2) * DH + gsw;
        const u16* gAH1 = xb + (size_t)(tAH1 >> 2) * DH + gsw;
        const u16* wbe  = wbt + ((size_t)e << 20);
        const u16* gBL0 = wbe + (size_t)(n0 + BLb * 8 + crow) * DH + gsw;
        const u16* gBL1 = gBL0 + (size_t)8 * DH;
        const u16* gBH0 = wbe + (size_t)(n0 + BHb * 8 + crow) * DH + gsw;
        const u16* gBH1 = gBH0 + (size_t)8 * DH;

        f32x4 acc[8][4] = {};

        #pragma unroll
        for (int kt = 0; kt < 2; kt++) {
            const int ko = kt * 64; const int p = kt;
            glds16(gAL0 + ko, &As[p][ALb * 512]); glds16(gAL1 + ko, &As[p][(ALb + 1) * 512]);
            glds16(gAH0 + ko, &As[p][AHb * 512]); glds16(gAH1 + ko, &As[p][(AHb + 1) * 512]);
            glds16(gBL0 + ko, &Bs[p][BLb * 512]); glds16(gBL1 + ko, &Bs[p][(BLb + 1) * 512]);
            glds16(gBH0 + ko, &Bs[p][BHb * 512]); glds16(gBH1 + ko, &Bs[p][(BHb + 1) * 512]);
        }
        WAITVM(8);            // tile 0 resident (tile 1 in flight)
        SBAR();

        const int arow = (wr * 128 + fr) * 64;    // u16 base of this lane's A frag rows
        const int brow = (wc * 64  + fr) * 64;
        const int c0 = fq ^ swz;                  // k-half 0 column (u16)
        const int c1 = (32 + fq) ^ swz;           // k-half 1 column

        bf16x8 afL[4][2], afH[4][2], bfL[2][2], bfH[2][2];

        for (int kt = 0; kt < 16; ++kt) {
            const int p = kt & 1;
            const u16* Ap = &As[p][0];
            const u16* Bp = &Bs[p][0];

            // ---- P1: read afL(8)+bfL(4); stage A-H of kt+1 -> buf p^1; MFMA miL x njL ----
            #pragma unroll
            for (int mi = 0; mi < 4; mi++) {
                afL[mi][0] = *(const bf16x8*)&Ap[arow + mi * 1024 + c0];
                afL[mi][1] = *(const bf16x8*)&Ap[arow + mi * 1024 + c1];
            }
            #pragma unroll
            for (int nj = 0; nj < 2; nj++) {
                bfL[nj][0] = *(const bf16x8*)&Bp[brow + nj * 1024 + c0];
                bfL[nj][1] = *(const bf16x8*)&Bp[brow + nj * 1024 + c1];
            }
            if (kt >= 1 && kt <= 14) {             // A-H rows of p^1 died at end-P3 of kt-1
                const int ko = (kt + 1) * 64; const int q = (kt + 1) & 1;
                glds16(gAH0 + ko, &As[q][AHb * 512]);
                glds16(gAH1 + ko, &As[q][(AHb + 1) * 512]);
            }
            asm volatile("s_waitcnt lgkmcnt(8)" ::: "memory");   // 12-read phase hint (template)
            SBAR(); WAITLGKM0();
            __builtin_amdgcn_s_setprio(1);
            #pragma unroll
            for (int mi = 0; mi < 4; mi++)
                #pragma unroll
                for (int nj = 0; nj < 2; nj++) {
                    acc[mi][nj] = __builtin_amdgcn_mfma_f32_16x16x32_bf16(afL[mi][0], bfL[nj][0], acc[mi][nj], 0, 0, 0);
                    acc[mi][nj] = __builtin_amdgcn_mfma_f32_16x16x32_bf16(afL[mi][1], bfL[nj][1], acc[mi][nj], 0, 0, 0);
                }
            __builtin_amdgcn_s_setprio(0);
            SBAR();                                // A-L/B-L rows of buf p now dead

            // ---- P2: read bfH(4); stage A-L of kt+2 -> buf p; MFMA miL x njH ----
            #pragma unroll
            for (int nj = 0; nj < 2; nj++) {
                bfH[nj][0] = *(const bf16x8*)&Bp[brow + (nj + 2) * 1024 + c0];
                bfH[nj][1] = *(const bf16x8*)&Bp[brow + (nj + 2) * 1024 + c1];
            }
            if (kt <= 13) {
                const int ko = (kt + 2) * 64;
                glds16(gAL0 + ko, &As[p][ALb * 512]);
                glds16(gAL1 + ko, &As[p][(ALb + 1) * 512]);
            }
            SBAR(); WAITLGKM0();
            __builtin_amdgcn_s_setprio(1);
            #pragma unroll
            for (int mi = 0; mi < 4; mi++)
                #pragma unroll
                for (int nj = 0; nj < 2; nj++) {
                    acc[mi][nj + 2] = __builtin_amdgcn_mfma_f32_16x16x32_bf16(afL[mi][0], bfH[nj][0], acc[mi][nj + 2], 0, 0, 0);
                    acc[mi][nj + 2] = __builtin_amdgcn_mfma_f32_16x16x32_bf16(afL[mi][1], bfH[nj][1], acc[mi][nj + 2], 0, 0, 0);
                }
            __builtin_amdgcn_s_setprio(0);
            SBAR();                                // B-H rows of buf p now dead

            // ---- P3: read afH(8); stage B-L of kt+2 -> buf p; MFMA miH x njH ----
            #pragma unroll
            for (int mi = 0; mi < 4; mi++) {
                afH[mi][0] = *(const bf16x8*)&Ap[arow + (mi + 4) * 1024 + c0];
                afH[mi][1] = *(const bf16x8*)&Ap[arow + (mi + 4) * 1024 + c1];
            }
            if (kt <= 13) {
                const int ko = (kt + 2) * 64;
                glds16(gBL0 + ko, &Bs[p][BLb * 512]);
                glds16(gBL1 + ko, &Bs[p][(BLb + 1) * 512]);
            }
            SBAR(); WAITLGKM0();
            __builtin_amdgcn_s_setprio(1);
            #pragma unroll
            for (int mi = 0; mi < 4; mi++)
                #pragma unroll
                for (int nj = 0; nj < 2; nj++) {
                    acc[mi + 4][nj + 2] = __builtin_amdgcn_mfma_f32_16x16x32_bf16(afH[mi][0], bfH[nj][0], acc[mi + 4][nj + 2], 0, 0, 0);
                    acc[mi + 4][nj + 2] = __builtin_amdgcn_mfma_f32_16x16x32_bf16(afH[mi][1], bfH[nj][1], acc[mi + 4][nj + 2], 0, 0, 0);
                }
            __builtin_amdgcn_s_setprio(0);
            SBAR();                                // A-H rows of buf p now dead

            // ---- P4: stage B-H of kt+2 -> buf p; MFMA miH x njL (regs only); counted vmcnt ----
            if (kt <= 13) {
                const int ko = (kt + 2) * 64;
                glds16(gBH0 + ko, &Bs[p][BHb * 512]);
                glds16(gBH1 + ko, &Bs[p][(BHb + 1) * 512]);
            }
            __builtin_amdgcn_s_setprio(1);
            #pragma unroll
            for (int mi = 0; mi < 4; mi++)
                #pragma unroll
                for (int nj = 0; nj < 2; nj++) {
                    acc[mi + 4][nj] = __builtin_amdgcn_mfma_f32_16x16x32_bf16(afH[mi][0], bfL[nj][0], acc[mi + 4][nj], 0, 0, 0);
                    acc[mi + 4][nj] = __builtin_amdgcn_mfma_f32_16x16x32_bf16(afH[mi][1], bfL[nj][1], acc[mi + 4][nj], 0, 0, 0);
                }
            __builtin_amdgcn_s_setprio(0);
            // newer-than-(kt+1) loads = kt+2's A-L,B-L,B-H = 6 -> vmcnt(6) => tile kt+1 resident
            if (kt <= 13)      WAITVM(6);
            else if (kt == 14) WAITVM(0);          // drain for tile 15
            SBAR();
        }

        // C/D layout: col = lane&15, row = (lane>>4)*4 + r
        const int cl = lane & 15;
        const int rb = (lane >> 4) * 4;
        #pragma unroll
        for (int mi = 0; mi < 8; mi++) {
            #pragma unroll
            for (int r = 0; r < 4; r++) {
                const int srow = wr * 128 + mi * 16 + rb + r;
                const int tok = s_tok[srow];
                const float w = s_w[srow];
                u16* yr = y + (size_t)tok * DH + (n0 + wc * 64 + cl);
                #pragma unroll
                for (int nj = 0; nj < 4; nj++)
                    yr[nj * 16] = f2b(acc[mi][nj][r] * w);
            }
        }
    }
}

// ---------------- combine: out[t] = sum_k y[t*4+k] + sum_k w_k*b[e_k]; block 0 does aux ----------------
__global__ __launch_bounds__(256) void combine_kernel(
    const u16* __restrict__ y, const int* __restrict__ tk_e, const float* __restrict__ tk_w,
    const float* __restrict__ bexp,
    const int* __restrict__ cnt, const float* __restrict__ probsum,
    float* __restrict__ out, float* __restrict__ out_aux)
{
    if (blockIdx.x == 0 && threadIdx.x == 0) {
        float s = 0.f;
        for (int e = 0; e < NE; e++) s += (float)cnt[e] * probsum[e];
        out_aux[0] = s * (float)NE / ((float)T_TOK * (float)T_TOK);
    }
    const int t = blockIdx.x * 2 + (threadIdx.x >> 7);
    const int c = (threadIdx.x & 127) * 8;
    float o[8] = {};
    #pragma unroll
    for (int k = 0; k < TK; k++) {
        const int e   = tk_e[t * TK + k];
        const float w = tk_w[t * TK + k];
        const u16* yp = y + ((size_t)(t * TK + k)) * DH + c;
        const ushort4 y0 = *(const ushort4*)(yp);
        const ushort4 y1 = *(const ushort4*)(yp + 4);
        const float4  b0 = *(const float4*)(bexp + (size_t)e * DH + c);
        const float4  b1 = *(const float4*)(bexp + (size_t)e * DH + c + 4);
        o[0] += b2f(y0.x) + w * b0.x;
        o[1] += b2f(y0.y) + w * b0.y;
        o[2] += b2f(y0.z) + w * b0.z;
        o[3] += b2f(y0.w) + w * b0.w;
        o[4] += b2f(y1.x) + w * b1.x;
        o[5] += b2f(y1.y) + w * b1.y;
        o[6] += b2f(y1.z) + w * b1.z;
        o[7] += b2f(y1.w) + w * b1.w;
    }
    float4 ov0 = {o[0], o[1], o[2], o[3]};
    float4 ov1 = {o[4], o[5], o[6], o[7]};
    *(float4*)(out + (size_t)t * DH + c)     = ov0;
    *(float4*)(out + (size_t)t * DH + c + 4) = ov1;
}

extern "C" void kernel_launch(void* const* d_in, const int* in_sizes, int n_in,
                              void* d_out, int out_size, void* d_ws, size_t ws_size,
                              hipStream_t stream)
{
    const float* x  = (const float*)d_in[0];
    const float* Wg = (const float*)d_in[1];
    const float* bg = (const float*)d_in[2];
    const float* W  = (const float*)d_in[3];
    const float* b  = (const float*)d_in[4];
    float* out = (float*)d_out;

    char* ws = (char*)d_ws;
    u16*   xb         = (u16*)(ws);                    // 16,777,216 B
    u16*   wbt        = (u16*)(ws + 16777216);         // 16,777,216 B
    u16*   y          = (u16*)(ws + 33554432);         // 67,108,864 B
    int*   bucket_tok = (int*)(ws + 100663296);        //    262,144 B
    float* bucket_w   = (float*)(ws + 100925440);      //    262,144 B
    int*   tk_e       = (int*)(ws + 101187584);        //    131,072 B
    float* tk_w       = (float*)(ws + 101318656);      //    131,072 B
    int*   cnt        = (int*)(ws + 101449728);        //         32 B
    float* probsum    = (float*)(ws + 101449760);      //         32 B

    hipMemsetAsync(cnt, 0, 64, stream);  // cnt + probsum (must precede router atomics)

    prep_kernel<<<2048, 512, 0, stream>>>(W, wbt, x, Wg, bg, xb,
                                          bucket_tok, bucket_w, tk_e, tk_w, cnt, probsum);
    moe_gemm_kernel<<<dim3(384), 512, 0, stream>>>(xb, wbt, bucket_tok, bucket_w, cnt, y);
    combine_kernel<<<4096, 256, 0, stream>>>(y, tk_e, tk_w, b, cnt, probsum, out, out + (size_t)T_TOK * DH);
}